// Round 14
// baseline (262.319 us; speedup 1.0000x reference)
//
#include <hip/hip_runtime.h>
#include <hip/hip_bf16.h>
#include <cstddef>

#define D_MODEL   384
#define D_IN_PROJ 1676
#define D_INNER   768
#define D_CONV_IN 896
#define ZXLD      1664
#define NPROJPAD  1792          // 14 * 128
#define NHEADS    12
#define HEADDIM   64
#define D_STATE   64
#define SEQLEN    4096
#define BATCH     8
#define NTOK      (BATCH * SEQLEN)
#define EPSV      1e-5f
#define Q         128
#define NCHUNK    (SEQLEN / Q)
#define NCHB      (BATCH * NHEADS * NCHUNK)
#define NBC       (BATCH * NCHUNK)

typedef __hip_bfloat16 bf16;
typedef __attribute__((ext_vector_type(8))) short bf16x8v;
typedef __attribute__((ext_vector_type(4))) float f32x4v;

__device__ __forceinline__ float b2f(bf16 v) { return __bfloat162float(v); }
__device__ __forceinline__ bf16  f2b(float v) { return __float2bfloat16(v); }
__device__ __forceinline__ float bl(unsigned u)  { return __uint_as_float(u << 16); }
__device__ __forceinline__ float bh(unsigned u)  { return __uint_as_float(u & 0xffff0000u); }
__device__ __forceinline__ float bu(unsigned short v) { return __uint_as_float(((unsigned)v) << 16); }
__device__ __forceinline__ unsigned pk2(float a, float b) {
    return ((unsigned)__bfloat16_as_ushort(f2b(b)) << 16) | (unsigned)__bfloat16_as_ushort(f2b(a));
}
__device__ __forceinline__ int swzf(int r) { return (r ^ (r >> 2)) & 3; }
__device__ __forceinline__ int tswz(int r, int col) {
    return r * 128 + ((((col >> 3) ^ (r & 7)) << 3) | (col & 7));
}

#define GL_LDS16(g, l) __builtin_amdgcn_global_load_lds( \
    (const __attribute__((address_space(1))) unsigned*)(g), \
    (__attribute__((address_space(3))) unsigned*)(l), 16, 0, 0)

// ---------------------------------------------------------------------------
__global__ __launch_bounds__(256)
void cvt_f32_bf16(const float* __restrict__ in, unsigned short* __restrict__ out, int n) {
    int i = (blockIdx.x * 256 + threadIdx.x) * 4;
    if (i + 3 < n) {
        float4 v = *(const float4*)(in + i);
        uint2 o; o.x = pk2(v.x, v.y); o.y = pk2(v.z, v.w);
        *(uint2*)(out + i) = o;
    }
}

__global__ __launch_bounds__(256)
void cvt_pad(const float* __restrict__ in, unsigned short* __restrict__ out,
             int n_real, int n_pad) {
    int i = (blockIdx.x * 256 + threadIdx.x) * 4;
    if (i + 3 < n_pad) {
        uint2 o;
        if (i < n_real) {
            float4 v = *(const float4*)(in + i);
            o.x = pk2(v.x, v.y); o.y = pk2(v.z, v.w);
        } else {
            o.x = 0u; o.y = 0u;
        }
        *(uint2*)(out + i) = o;
    }
}

// ---------------------------------------------------------------------------
// K1: MFMA GEMM-NT, 256x128 tile, 512 threads, BK=32 dbuf, XCD remap
// ---------------------------------------------------------------------------
__global__ __launch_bounds__(512)
void gemm_in_256(const bf16* __restrict__ A, const bf16* __restrict__ Bw,
                 bf16* __restrict__ Zo, bf16* __restrict__ XBCo,
                 float* __restrict__ Do) {
    const int K = D_MODEL;
    __shared__ short As[2][256 * 32];
    __shared__ short Bs[2][128 * 32];
    const int tid = threadIdx.x;
    const int lane = tid & 63;
    const int wv = tid >> 6;
    const int wr = wv >> 1;
    const int wc = wv & 1;

    const int id = blockIdx.x;
    const int xcd = id & 7;
    const int j = id >> 3;
    const int by = xcd + 8 * (j / 14);
    const int bx = j % 14;
    const int bm = by * 256;
    const int bn = bx * 128;

    f32x4v acc[4][4];
#pragma unroll
    for (int mi = 0; mi < 4; ++mi)
#pragma unroll
        for (int ni = 0; ni < 4; ++ni)
            acc[mi][ni] = (f32x4v){0.f, 0.f, 0.f, 0.f};

    int aoff[2], boff;
#pragma unroll
    for (int q = 0; q < 2; ++q) {
        int o = q * 8192 + tid * 16;
        int row = o >> 6;
        int ps = (o >> 4) & 3;
        int sl = ps ^ swzf(row);
        aoff[q] = (bm + row) * K + sl * 8;
    }
    {
        int o = tid * 16;
        int row = o >> 6;
        int ps = (o >> 4) & 3;
        int sl = ps ^ swzf(row);
        boff = (bn + row) * K + sl * 8;
    }

    const int l15 = lane & 15, qq = lane >> 4;
    int aidx[4], bidx[4];
#pragma unroll
    for (int i = 0; i < 4; ++i) {
        int ra = wr * 64 + i * 16 + l15;
        int rb = wc * 64 + i * 16 + l15;
        aidx[i] = ra * 32 + ((qq ^ swzf(ra)) * 8);
        bidx[i] = rb * 32 + ((qq ^ swzf(rb)) * 8);
    }

    GL_LDS16(A + (size_t)aoff[0], &As[0][tid * 8]);
    GL_LDS16(A + (size_t)aoff[1], &As[0][4096 + tid * 8]);
    GL_LDS16(Bw + (size_t)boff, &Bs[0][tid * 8]);
    __syncthreads();

    const int nt = K >> 5;
    for (int t = 0; t < nt; ++t) {
        const int cur = t & 1;
        if (t + 1 < nt) {
            const int k0 = (t + 1) << 5;
            GL_LDS16(A + (size_t)aoff[0] + k0, &As[cur ^ 1][tid * 8]);
            GL_LDS16(A + (size_t)aoff[1] + k0, &As[cur ^ 1][4096 + tid * 8]);
            GL_LDS16(Bw + (size_t)boff + k0, &Bs[cur ^ 1][tid * 8]);
        }
        bf16x8v af[4], bf[4];
#pragma unroll
        for (int i = 0; i < 4; ++i) {
            af[i] = *(const bf16x8v*)(&As[cur][aidx[i]]);
            bf[i] = *(const bf16x8v*)(&Bs[cur][bidx[i]]);
        }
#pragma unroll
        for (int mi = 0; mi < 4; ++mi)
#pragma unroll
            for (int ni = 0; ni < 4; ++ni)
                acc[mi][ni] = __builtin_amdgcn_mfma_f32_16x16x32_bf16(
                    af[mi], bf[ni], acc[mi][ni], 0, 0, 0);
        __syncthreads();
    }

    const int l4 = lane >> 4;
#pragma unroll
    for (int mi = 0; mi < 4; ++mi) {
        int rbase = bm + wr * 64 + mi * 16 + l4 * 4;
#pragma unroll
        for (int ni = 0; ni < 4; ++ni) {
            int col = bn + wc * 64 + ni * 16 + l15;
            f32x4v v = acc[mi][ni];
            if (col < D_INNER) {
#pragma unroll
                for (int jj = 0; jj < 4; ++jj)
                    Zo[(size_t)(rbase + jj) * D_INNER + col] = f2b(v[jj]);
            } else if (col < ZXLD) {
#pragma unroll
                for (int jj = 0; jj < 4; ++jj)
                    XBCo[(size_t)(rbase + jj) * D_CONV_IN + (col - D_INNER)] = f2b(v[jj]);
            } else if (col < D_IN_PROJ) {
#pragma unroll
                for (int jj = 0; jj < 4; ++jj)
                    Do[(size_t)(rbase + jj) * NHEADS + (col - ZXLD)] = v[jj];
            }
        }
    }
}

// ---------------------------------------------------------------------------
// K4: MFMA GEMM-NT 128x128, BK=32 dbuf, XCD remap (unchanged)
// ---------------------------------------------------------------------------
template<int NX>
__global__ __launch_bounds__(256)
void gemm_out_mfma(const bf16* __restrict__ A, const bf16* __restrict__ Bw, int K,
                   float* __restrict__ Co) {
    __shared__ short As[2][128 * 32];
    __shared__ short Bs[2][128 * 32];
    const int tid = threadIdx.x;
    const int lane = tid & 63;
    const int w = tid >> 6;
    const int wr = w >> 1, wc = w & 1;

    const int id = blockIdx.x;
    const int xcd = id & 7;
    const int j = id >> 3;
    const int by = xcd + 8 * (j / NX);
    const int bx = j % NX;
    const int bm = by * 128;
    const int bn = bx * 128;

    f32x4v acc[4][4];
#pragma unroll
    for (int mi = 0; mi < 4; ++mi)
#pragma unroll
        for (int ni = 0; ni < 4; ++ni)
            acc[mi][ni] = (f32x4v){0.f, 0.f, 0.f, 0.f};

    int aoff[2], boff[2];
#pragma unroll
    for (int q = 0; q < 2; ++q) {
        int o = q * 4096 + tid * 16;
        int row = o >> 6;
        int ps = (o >> 4) & 3;
        int sl = ps ^ swzf(row);
        aoff[q] = (bm + row) * K + sl * 8;
        boff[q] = (bn + row) * K + sl * 8;
    }

    const int l15 = lane & 15, qq = lane >> 4;
    int aidx[4], bidx[4];
#pragma unroll
    for (int i = 0; i < 4; ++i) {
        int ra = wr * 64 + i * 16 + l15;
        int rb = wc * 64 + i * 16 + l15;
        aidx[i] = ra * 32 + ((qq ^ swzf(ra)) * 8);
        bidx[i] = rb * 32 + ((qq ^ swzf(rb)) * 8);
    }

    GL_LDS16(A + (size_t)aoff[0], &As[0][tid * 8]);
    GL_LDS16(A + (size_t)aoff[1], &As[0][2048 + tid * 8]);
    GL_LDS16(Bw + (size_t)boff[0], &Bs[0][tid * 8]);
    GL_LDS16(Bw + (size_t)boff[1], &Bs[0][2048 + tid * 8]);
    __syncthreads();

    const int nt = K >> 5;
    for (int t = 0; t < nt; ++t) {
        const int cur = t & 1;
        if (t + 1 < nt) {
            const int k0 = (t + 1) << 5;
            GL_LDS16(A + (size_t)aoff[0] + k0, &As[cur ^ 1][tid * 8]);
            GL_LDS16(A + (size_t)aoff[1] + k0, &As[cur ^ 1][2048 + tid * 8]);
            GL_LDS16(Bw + (size_t)boff[0] + k0, &Bs[cur ^ 1][tid * 8]);
            GL_LDS16(Bw + (size_t)boff[1] + k0, &Bs[cur ^ 1][2048 + tid * 8]);
        }
        bf16x8v af[4], bf[4];
#pragma unroll
        for (int i = 0; i < 4; ++i) {
            af[i] = *(const bf16x8v*)(&As[cur][aidx[i]]);
            bf[i] = *(const bf16x8v*)(&Bs[cur][bidx[i]]);
        }
#pragma unroll
        for (int mi = 0; mi < 4; ++mi)
#pragma unroll
            for (int ni = 0; ni < 4; ++ni)
                acc[mi][ni] = __builtin_amdgcn_mfma_f32_16x16x32_bf16(
                    af[mi], bf[ni], acc[mi][ni], 0, 0, 0);
        __syncthreads();
    }

    const int l4 = lane >> 4;
#pragma unroll
    for (int mi = 0; mi < 4; ++mi) {
        int rbase = bm + wr * 64 + mi * 16 + l4 * 4;
#pragma unroll
        for (int ni = 0; ni < 4; ++ni) {
            int col = bn + wc * 64 + ni * 16 + l15;
            f32x4v v = acc[mi][ni];
#pragma unroll
            for (int jj = 0; jj < 4; ++jj)
                Co[(size_t)(rbase + jj) * D_MODEL + col] = v[jj];
        }
    }
}

// ---------------------------------------------------------------------------
// K2 v3 (unchanged)
// ---------------------------------------------------------------------------
__global__ __launch_bounds__(256)
void conv_norm_v3(const bf16* __restrict__ XBC, const float* __restrict__ dtraw,
                  const float* __restrict__ conv_w, const float* __restrict__ conv_b,
                  const float* __restrict__ norm_w, const float* __restrict__ dt_bias,
                  bf16* __restrict__ xn, bf16* __restrict__ Bb,
                  bf16* __restrict__ Cb, float* __restrict__ dtb) {
    const int tid = threadIdx.x;
    const int t0 = blockIdx.x * 8;
    const int l0 = t0 & (SEQLEN - 1);

    __shared__ float sp[8][200];
    __shared__ float sq[8][8];
    __shared__ float sscale[8];

    const int c = tid;
    const bool active = (c < 224);
    const int ch0 = c * 4;

    float acc[8][4];
    float w0[4], w1[4], w2[4], w3[4];

    if (active) {
        float4 wa = *(const float4*)(conv_w + (ch0 + 0) * 4);
        float4 wb = *(const float4*)(conv_w + (ch0 + 1) * 4);
        float4 wcc = *(const float4*)(conv_w + (ch0 + 2) * 4);
        float4 wd = *(const float4*)(conv_w + (ch0 + 3) * 4);
        w0[0] = wa.x; w1[0] = wa.y; w2[0] = wa.z; w3[0] = wa.w;
        w0[1] = wb.x; w1[1] = wb.y; w2[1] = wb.z; w3[1] = wb.w;
        w0[2] = wcc.x; w1[2] = wcc.y; w2[2] = wcc.z; w3[2] = wcc.w;
        w0[3] = wd.x; w1[3] = wd.y; w2[3] = wd.z; w3[3] = wd.w;
        float4 bv = *(const float4*)(conv_b + ch0);
#pragma unroll
        for (int t = 0; t < 8; ++t) {
            acc[t][0] = bv.x; acc[t][1] = bv.y; acc[t][2] = bv.z; acc[t][3] = bv.w;
        }
#pragma unroll
        for (int ri = 0; ri < 11; ++ri) {
            int lr = l0 - 3 + ri;
            if (lr >= 0) {
                uint2 rv = *(const uint2*)((const unsigned short*)XBC
                              + (size_t)(t0 - 3 + ri) * D_CONV_IN + ch0);
                float r0 = bl(rv.x), r1 = bh(rv.x), r2 = bl(rv.y), r3 = bh(rv.y);
#pragma unroll
                for (int t = 0; t < 8; ++t) {
                    if (t >= ri - 3 && t <= ri) {
                        const int jt = ri - t;
                        const float* wj = (jt == 0) ? w0 : (jt == 1) ? w1 : (jt == 2) ? w2 : w3;
                        acc[t][0] += r0 * wj[0];
                        acc[t][1] += r1 * wj[1];
                        acc[t][2] += r2 * wj[2];
                        acc[t][3] += r3 * wj[3];
                    }
                }
            }
        }
#pragma unroll
        for (int t = 0; t < 8; ++t) {
            float ss = 0.f;
#pragma unroll
            for (int i = 0; i < 4; ++i) {
                float v = acc[t][i];
                float s = v / (1.f + __expf(-v));
                acc[t][i] = s;
                ss += s * s;
            }
            if (c < 192) sp[t][c] = ss;
        }
    }
    __syncthreads();
    if (tid < 64) {
        int t = tid >> 3, i = tid & 7;
        float s = 0.f;
#pragma unroll
        for (int k = 0; k < 24; ++k) s += sp[t][i * 24 + k];
        sq[t][i] = s;
    }
    __syncthreads();
    if (tid < 8) {
        float tot = 0.f;
#pragma unroll
        for (int i = 0; i < 8; ++i) tot += sq[tid][i];
        sscale[tid] = rsqrtf(tot / (float)D_INNER + EPSV);
    }
    __syncthreads();

    if (c < 192) {
        float4 nv = *(const float4*)(norm_w + ch0);
#pragma unroll
        for (int t = 0; t < 8; ++t) {
            float sc = sscale[t];
            uint2 o;
            o.x = pk2(acc[t][0] * sc * nv.x, acc[t][1] * sc * nv.y);
            o.y = pk2(acc[t][2] * sc * nv.z, acc[t][3] * sc * nv.w);
            *(uint2*)(xn + (size_t)(t0 + t) * D_INNER + ch0) = o;
        }
    } else if (c < 224) {
        const int idx = ch0 - 768;
#pragma unroll
        for (int t = 0; t < 8; ++t) {
            uint2 o;
            o.x = pk2(acc[t][0], acc[t][1]);
            o.y = pk2(acc[t][2], acc[t][3]);
            bf16* base = (idx < 64) ? (Bb + (size_t)(t0 + t) * D_STATE + idx)
                                    : (Cb + (size_t)(t0 + t) * D_STATE + (idx - 64));
            *(uint2*)base = o;
        }
    }
    if (tid < 96) {
        int t = tid / 12, hh = tid % 12;
        float v = dtraw[(size_t)(t0 + t) * NHEADS + hh] + dt_bias[hh];
        float spv = (v > 20.f) ? v : log1pf(expf(v));
        dtb[(size_t)(t0 + t) * NHEADS + hh] = spv;
    }
}

// ---------------------------------------------------------------------------
// Score kernel (unchanged)
// ---------------------------------------------------------------------------
__global__ __launch_bounds__(256)
void score_kernel(const bf16* __restrict__ Bb, const bf16* __restrict__ Cb,
                  bf16* __restrict__ Graw) {
    const int bc = blockIdx.x;
    const size_t tok0 = (size_t)bc * Q;
    const int tid = threadIdx.x;
    const int lane = tid & 63, w = tid >> 6;
    const int wr = w >> 1, wc = w & 1;
    __shared__ short sC[Q * 64];
    __shared__ short sB[Q * 64];

#pragma unroll
    for (int it = 0; it < 4; ++it) {
        int j = it * 256 + tid;
        int r = j >> 3, sp = j & 7;
        int sl = sp ^ (r & 7);
        GL_LDS16(Cb + tok0 * D_STATE + r * 64 + sl * 8, sC + j * 8);
        GL_LDS16(Bb + tok0 * D_STATE + r * 64 + sl * 8, sB + j * 8);
    }
    __syncthreads();

    const int l15 = lane & 15, qq = lane >> 4;
    f32x4v acc[4][4];
#pragma unroll
    for (int mi = 0; mi < 4; ++mi)
#pragma unroll
        for (int ni = 0; ni < 4; ++ni)
            acc[mi][ni] = (f32x4v){0.f, 0.f, 0.f, 0.f};

#pragma unroll
    for (int kb = 0; kb < 2; ++kb) {
        bf16x8v af[4], bf[4];
#pragma unroll
        for (int i = 0; i < 4; ++i) {
            int ra = wr * 64 + i * 16 + l15;
            int rb = wc * 64 + i * 16 + l15;
            af[i] = *(const bf16x8v*)(sC + ra * 64 + ((kb * 4 + qq) ^ (ra & 7)) * 8);
            bf[i] = *(const bf16x8v*)(sB + rb * 64 + ((kb * 4 + qq) ^ (rb & 7)) * 8);
        }
#pragma unroll
        for (int mi = 0; mi < 4; ++mi)
#pragma unroll
            for (int ni = 0; ni < 4; ++ni)
                acc[mi][ni] = __builtin_amdgcn_mfma_f32_16x16x32_bf16(
                    af[mi], bf[ni], acc[mi][ni], 0, 0, 0);
    }

    bf16* gout = Graw + (size_t)bc * (Q * Q);
#pragma unroll
    for (int mi = 0; mi < 4; ++mi) {
        int t0 = wr * 64 + mi * 16 + qq * 4;
#pragma unroll
        for (int ni = 0; ni < 4; ++ni) {
            int s = wc * 64 + ni * 16 + l15;
            f32x4v v = acc[mi][ni];
#pragma unroll
            for (int j = 0; j < 4; ++j)
                gout[(size_t)(t0 + j) * Q + s] = f2b(v[j]);
        }
    }
}

// ---------------------------------------------------------------------------
// K3a (MFMA) (unchanged)
// ---------------------------------------------------------------------------
__global__ __launch_bounds__(256)
void chunk_state_mfma(const bf16* __restrict__ xy, const bf16* __restrict__ Bb,
                      const float* __restrict__ dtb, const float* __restrict__ A_log,
                      float* __restrict__ states, float* __restrict__ cdecay) {
    const int sid = blockIdx.x;
    const int c = sid % NCHUNK;
    const int h = (sid / NCHUNK) % NHEADS;
    const int b = sid / (NCHUNK * NHEADS);
    const int tid = threadIdx.x;
    const int lane = tid & 63, w = tid >> 6;
    const size_t tok0 = (size_t)b * SEQLEN + (size_t)c * Q;
    const float Acoef = -expf(A_log[h]);

    __shared__ __align__(16) unsigned short sBT[64 * 128];
    __shared__ __align__(16) unsigned short sXT[64 * 128];
    __shared__ float slcum[Q];
    __shared__ float sdt[Q];
    __shared__ float wtot[2];

    float lx = 0.f;
    if (tid < Q) {
        float dtv = dtb[(tok0 + tid) * NHEADS + h];
        sdt[tid] = dtv;
        lx = dtv * Acoef;
        int ln = tid & 63;
        for (int off = 1; off < 64; off <<= 1) {
            float v = __shfl_up(lx, off, 64);
            if (ln >= off) lx += v;
        }
        if (ln == 63) wtot[tid >> 6] = lx;
    }
    __syncthreads();
    if (tid < Q) {
        if (tid >= 64) lx += wtot[0];
        slcum[tid] = lx;
    }
    __syncthreads();
    const float ltot = slcum[Q - 1];

    {
        int t = tid >> 1, half = tid & 1;
        float s_t = sdt[t] * __expf(ltot - slcum[t]);
        const unsigned short* br = (const unsigned short*)(Bb + (tok0 + t) * D_STATE) + half * 32;
        const unsigned short* xr = (const unsigned short*)(xy + (tok0 + t) * D_INNER + h * HEADDIM) + half * 32;
#pragma unroll
        for (int i = 0; i < 32; ++i) {
            int r = half * 32 + i;
            sBT[tswz(r, t)] = __bfloat16_as_ushort(f2b(bu(br[i]) * s_t));
            sXT[tswz(r, t)] = xr[i];
        }
    }
    __syncthreads();

    const int l15 = lane & 15, qq = lane >> 4;
    f32x4v acc[4];
#pragma unroll
    for (int ni = 0; ni < 4; ++ni) acc[ni] = (f32x4v){0.f, 0.f, 0.f, 0.f};

#pragma unroll
    for (int kb = 0; kb < 4; ++kb) {
        const int col = kb * 32 + qq * 8;
        bf16x8v af = *(const bf16x8v*)(&sBT[tswz(w * 16 + l15, col)]);
#pragma unroll
        for (int ni = 0; ni < 4; ++ni) {
            bf16x8v bx = *(const bf16x8v*)(&sXT[tswz(ni * 16 + l15, col)]);
            acc[ni] = __builtin_amdgcn_mfma_f32_16x16x32_bf16(af, bx, acc[ni], 0, 0, 0);
        }
    }

    float* out = states + (size_t)sid * 4096;
#pragma unroll
    for (int ni = 0; ni < 4; ++ni) {
#pragma unroll
        for (int j = 0; j < 4; ++j) {
            int n = w * 16 + qq * 4 + j;
            int p = ni * 16 + l15;
            out[n * 64 + p] = acc[ni][j];
        }
    }
    if (tid == 0) cdecay[sid] = expf(ltot);
}

// ---------------------------------------------------------------------------
// K3b (unchanged)
// ---------------------------------------------------------------------------
__global__ __launch_bounds__(256)
void state_pass_kernel(float* __restrict__ states, const float* __restrict__ cdecay) {
    const int bh = blockIdx.x;
    const int tid = threadIdx.x;
    float run[16];
#pragma unroll
    for (int i = 0; i < 16; ++i) run[i] = 0.f;
    float* base = states + (size_t)bh * NCHUNK * 4096 + tid * 16;
    const float* cd = cdecay + bh * NCHUNK;
    for (int c = 0; c < NCHUNK; ++c) {
        float dec = cd[c];
        float* ptr = base + (size_t)c * 4096;
        float4 s0 = *(float4*)(ptr + 0);
        float4 s1 = *(float4*)(ptr + 4);
        float4 s2 = *(float4*)(ptr + 8);
        float4 s3 = *(float4*)(ptr + 12);
        float nr[16];
        nr[0] = dec * run[0] + s0.x;  nr[1] = dec * run[1] + s0.y;
        nr[2] = dec * run[2] + s0.z;  nr[3] = dec * run[3] + s0.w;
        nr[4] = dec * run[4] + s1.x;  nr[5] = dec * run[5] + s1.y;
        nr[6] = dec * run[6] + s1.z;  nr[7] = dec * run[7] + s1.w;
        nr[8] = dec * run[8] + s2.x;  nr[9] = dec * run[9] + s2.y;
        nr[10] = dec * run[10] + s2.z; nr[11] = dec * run[11] + s2.w;
        nr[12] = dec * run[12] + s3.x; nr[13] = dec * run[13] + s3.y;
        nr[14] = dec * run[14] + s3.z; nr[15] = dec * run[15] + s3.w;
        *(float4*)(ptr + 0)  = make_float4(run[0], run[1], run[2], run[3]);
        *(float4*)(ptr + 4)  = make_float4(run[4], run[5], run[6], run[7]);
        *(float4*)(ptr + 8)  = make_float4(run[8], run[9], run[10], run[11]);
        *(float4*)(ptr + 12) = make_float4(run[12], run[13], run[14], run[15]);
#pragma unroll
        for (int i = 0; i < 16; ++i) run[i] = nr[i];
    }
}

// ---------------------------------------------------------------------------
// K3c v3 (MFMA): head-clustered XCD remap + paired (u32) transpose staging.
// ---------------------------------------------------------------------------
__global__ __launch_bounds__(256)
void chunk_output_mfma(const bf16* __restrict__ Zb, bf16* __restrict__ xy,
                       const bf16* __restrict__ Cb, const bf16* __restrict__ Graw,
                       const float* __restrict__ dtb, const float* __restrict__ A_log,
                       const float* __restrict__ Dpa, const float* __restrict__ states) {
    // head-clustered bijective remap: all 12 heads of one (b,c) on one XCD
    const int id = blockIdx.x;
    const int xcd = id & 7;
    const int jg = id >> 3;                 // 0..383
    const int bcg = xcd * 32 + (jg / NHEADS);   // 0..255
    const int h = jg % NHEADS;
    const int b = bcg / NCHUNK;
    const int c = bcg % NCHUNK;
    const int sid = (b * NHEADS + h) * NCHUNK + c;
    const int bc = bcg;
    const int tid = threadIdx.x;
    const int lane = tid & 63, w = tid >> 6;
    const size_t tok0 = (size_t)b * SEQLEN + (size_t)c * Q;
    const float Acoef = -expf(A_log[h]);

    __shared__ __align__(16) char smem[35840];
    unsigned short (*sXt)[136] = (unsigned short(*)[136])smem;
    unsigned short (*sNh)[72]  = (unsigned short(*)[72])(smem + 17408);
    unsigned short (*sNl)[72]  = (unsigned short(*)[72])(smem + 17408 + 9216);
    float (*sY)[68] = (float(*)[68])smem;
    __shared__ float slc[Q];
    __shared__ float sldn[Q];
    __shared__ float wtot[2];

    float lx = 0.f, l2dt = 0.f;
    if (tid < Q) {
        float dtv = dtb[(tok0 + tid) * NHEADS + h];
        l2dt = __logf(dtv);
        lx = dtv * Acoef;
        int ln = tid & 63;
        for (int off = 1; off < 64; off <<= 1) {
            float v = __shfl_up(lx, off, 64);
            if (ln >= off) lx += v;
        }
        if (ln == 63) wtot[tid >> 6] = lx;
    }
    __syncthreads();
    if (tid < Q) {
        if (tid >= 64) lx += wtot[0];
        slc[tid] = lx;
        sldn[tid] = lx - l2dt;
    }

    // --- stage X^T with paired u32 writes (conflict-free per wave) ---
    {
        int tp = tid & 63;            // t pair: t = 2*tp, 2*tp+1
        int rh = tid >> 6;            // rows [rh*16, rh*16+16)
        union { uint4 u[2]; unsigned short s[16]; } va, vb;
        const unsigned short* x0 = (const unsigned short*)(xy + (tok0 + 2 * tp) * D_INNER + h * HEADDIM + rh * 16);
        const unsigned short* x1 = (const unsigned short*)(xy + (tok0 + 2 * tp + 1) * D_INNER + h * HEADDIM + rh * 16);
        va.u[0] = *(const uint4*)(x0);  va.u[1] = *(const uint4*)(x0 + 8);
        vb.u[0] = *(const uint4*)(x1);  vb.u[1] = *(const uint4*)(x1 + 8);
#pragma unroll
        for (int i = 0; i < 16; ++i) {
            unsigned pack = (unsigned)va.s[i] | ((unsigned)vb.s[i] << 16);
            *(unsigned*)(&sXt[rh * 16 + i][2 * tp]) = pack;
        }
    }
    // --- stage init^T hi/lo ---
    {
        const float* init = states + (size_t)sid * 4096;
        for (int i = tid; i < 1024; i += 256) {
            float4 v = ((const float4*)init)[i];
            int n = i >> 4;
            int p = (i & 15) * 4;
#pragma unroll
            for (int j2 = 0; j2 < 4; ++j2) {
                float f = (&v.x)[j2];
                bf16 hi = f2b(f);
                float lo = f - b2f(hi);
                sNh[p + j2][n] = __bfloat16_as_ushort(hi);
                sNl[p + j2][n] = __bfloat16_as_ushort(f2b(lo));
            }
        }
    }
    __syncthreads();

    const int l15 = lane & 15, qq = lane >> 4;

    int tcur[2]; float lct_mi[2], elct[2];
#pragma unroll
    for (int mi = 0; mi < 2; ++mi) {
        tcur[mi] = w * 32 + mi * 16 + l15;
        lct_mi[mi] = slc[tcur[mi]];
        elct[mi] = __expf(lct_mi[mi]);
    }

    f32x4v acc[2][4];
#pragma unroll
    for (int mi = 0; mi < 2; ++mi)
#pragma unroll
        for (int ni = 0; ni < 4; ++ni)
            acc[mi][ni] = (f32x4v){0.f, 0.f, 0.f, 0.f};

    const bf16* grow = Graw + (size_t)bc * (Q * Q);

#pragma unroll
    for (int kb = 0; kb < 4; ++kb) {
        const int s0 = kb * 32 + qq * 8;
        float4 dA = *(const float4*)(sldn + s0);
        float4 dB = *(const float4*)(sldn + s0 + 4);
        bf16x8v af[2];
#pragma unroll
        for (int mi = 0; mi < 2; ++mi) {
            int t = tcur[mi];
            float lct = lct_mi[mi];
            uint4 gv = *(const uint4*)(grow + (size_t)t * Q + s0);
            float f0 = (s0 + 0 <= t) ? bl(gv.x) * __expf(lct - dA.x) : 0.f;
            float f1 = (s0 + 1 <= t) ? bh(gv.x) * __expf(lct - dA.y) : 0.f;
            float f2 = (s0 + 2 <= t) ? bl(gv.y) * __expf(lct - dA.z) : 0.f;
            float f3 = (s0 + 3 <= t) ? bh(gv.y) * __expf(lct - dA.w) : 0.f;
            float f4 = (s0 + 4 <= t) ? bl(gv.z) * __expf(lct - dB.x) : 0.f;
            float f5 = (s0 + 5 <= t) ? bh(gv.z) * __expf(lct - dB.y) : 0.f;
            float f6 = (s0 + 6 <= t) ? bl(gv.w) * __expf(lct - dB.z) : 0.f;
            float f7 = (s0 + 7 <= t) ? bh(gv.w) * __expf(lct - dB.w) : 0.f;
            union { bf16x8v v; unsigned u[4]; } r;
            r.u[0] = pk2(f0, f1); r.u[1] = pk2(f2, f3);
            r.u[2] = pk2(f4, f5); r.u[3] = pk2(f6, f7);
            af[mi] = r.v;
        }
        bf16x8v bfr[4];
#pragma unroll
        for (int ni = 0; ni < 4; ++ni)
            bfr[ni] = *(const bf16x8v*)(&sXt[ni * 16 + l15][s0]);
#pragma unroll
        for (int mi = 0; mi < 2; ++mi)
#pragma unroll
            for (int ni = 0; ni < 4; ++ni)
                acc[mi][ni] = __builtin_amdgcn_mfma_f32_16x16x32_bf16(
                    af[mi], bfr[ni], acc[mi][ni], 0, 0, 0);
    }

#pragma unroll
    for (int half = 0; half < 2; ++half) {
        const int n0 = half * 32 + qq * 8;
        bf16x8v af[2];
#pragma unroll
        for (int mi = 0; mi < 2; ++mi) {
            uint4 cv = *(const uint4*)(Cb + (tok0 + tcur[mi]) * D_STATE + n0);
            float el = elct[mi];
            union { bf16x8v v; unsigned u[4]; } r;
            r.u[0] = pk2(bl(cv.x) * el, bh(cv.x) * el);
            r.u[1] = pk2(bl(cv.y) * el, bh(cv.y) * el);
            r.u[2] = pk2(bl(cv.z) * el, bh(cv.z) * el);
            r.u[3] = pk2(bl(cv.w) * el, bh(cv.w) * el);
            af[mi] = r.v;
        }
        bf16x8v bh_[4], bl_[4];
#pragma unroll
        for (int ni = 0; ni < 4; ++ni) {
            int p = ni * 16 + l15;
            bh_[ni] = *(const bf16x8v*)(&sNh[p][n0]);
            bl_[ni] = *(const bf16x8v*)(&sNl[p][n0]);
        }
#pragma unroll
        for (int mi = 0; mi < 2; ++mi)
#pragma unroll
            for (int ni = 0; ni < 4; ++ni) {
                acc[mi][ni] = __builtin_amdgcn_mfma_f32_16x16x32_bf16(
                    af[mi], bh_[ni], acc[mi][ni], 0, 0, 0);
                acc[mi][ni] = __builtin_amdgcn_mfma_f32_16x16x32_bf16(
                    af[mi], bl_[ni], acc[mi][ni], 0, 0, 0);
            }
    }

    __syncthreads();
#pragma unroll
    for (int mi = 0; mi < 2; ++mi) {
        int r0 = w * 32 + mi * 16 + qq * 4;
#pragma unroll
        for (int ni = 0; ni < 4; ++ni) {
            int p = ni * 16 + l15;
            f32x4v v = acc[mi][ni];
#pragma unroll
            for (int jj = 0; jj < 4; ++jj) sY[r0 + jj][p] = v[jj];
        }
    }
    __syncthreads();

    {
        const float Dh = Dpa[h];
        int t = tid >> 1;
        int p0 = (tid & 1) * 32;
        size_t off = (tok0 + t) * D_INNER + h * HEADDIM + p0;
        const uint4* xrow = (const uint4*)(xy + off);
        const uint4* zrow = (const uint4*)(Zb + off);
        uint4 outv[4];
#pragma unroll
        for (int k4 = 0; k4 < 4; ++k4) {
            uint4 xv = xrow[k4];
            uint4 zv = zrow[k4];
            const float* yr = &sY[t][p0 + k4 * 8];
            float xs[8] = {bl(xv.x), bh(xv.x), bl(xv.y), bh(xv.y),
                           bl(xv.z), bh(xv.z), bl(xv.w), bh(xv.w)};
            float zs[8] = {bl(zv.x), bh(zv.x), bl(zv.y), bh(zv.y),
                           bl(zv.z), bh(zv.z), bl(zv.w), bh(zv.w)};
            unsigned o[4];
#pragma unroll
            for (int j = 0; j < 4; ++j) {
                float y0 = yr[2 * j]     + Dh * xs[2 * j];
                float y1 = yr[2 * j + 1] + Dh * xs[2 * j + 1];
                float z0 = zs[2 * j], z1 = zs[2 * j + 1];
                y0 *= z0 / (1.f + __expf(-z0));
                y1 *= z1 / (1.f + __expf(-z1));
                o[j] = pk2(y0, y1);
            }
            outv[k4].x = o[0]; outv[k4].y = o[1]; outv[k4].z = o[2]; outv[k4].w = o[3];
        }
        uint4* orow = (uint4*)(xy + off);
#pragma unroll
        for (int k4 = 0; k4 < 4; ++k4) orow[k4] = outv[k4];
    }
}

// ---------------------------------------------------------------------------
extern "C" void kernel_launch(void* const* d_in, const int* in_sizes, int n_in,
                              void* d_out, int out_size, void* d_ws, size_t ws_size,
                              hipStream_t stream) {
    (void)in_sizes; (void)n_in; (void)out_size; (void)ws_size;
    const float* u          = (const float*)d_in[0];
    const float* in_proj_w  = (const float*)d_in[1];
    const float* conv_w     = (const float*)d_in[2];
    const float* conv_b     = (const float*)d_in[3];
    const float* norm_w     = (const float*)d_in[4];
    const float* out_proj_w = (const float*)d_in[5];
    const float* A_log      = (const float*)d_in[6];
    const float* Dp         = (const float*)d_in[7];
    const float* dt_bias    = (const float*)d_in[8];

    char* w = (char*)d_ws;
    bf16*  Zb     = (bf16*)w;     w += (size_t)NTOK * D_INNER * 2;
    bf16*  XBC    = (bf16*)w;     w += (size_t)NTOK * D_CONV_IN * 2;
    bf16*  xy     = (bf16*)w;     w += (size_t)NTOK * D_INNER * 2;
    bf16*  Bb     = (bf16*)w;     w += (size_t)NTOK * D_STATE * 2;
    bf16*  Cb     = (bf16*)w;     w += (size_t)NTOK * D_STATE * 2;
    float* dtraw  = (float*)w;    w += (size_t)NTOK * NHEADS * 4;
    float* dtb    = (float*)w;    w += (size_t)NTOK * NHEADS * 4;
    float* cdecay = (float*)w;    w += (size_t)NCHB * 4;
    bf16*  wA     = (bf16*)w;     w += (size_t)NPROJPAD * D_MODEL * 2;
    bf16*  wO     = (bf16*)w;
    float* states = (float*)XBC;
    bf16*  Graw   = (bf16*)((char*)XBC + (size_t)NCHB * 4096 * 4);
    bf16*  uB     = xy;

    { int n = NTOK * D_MODEL;
      cvt_f32_bf16<<<(n / 4 + 255) / 256, 256, 0, stream>>>(u, (unsigned short*)uB, n); }
    { int nr = D_IN_PROJ * D_MODEL, np = NPROJPAD * D_MODEL;
      cvt_pad<<<(np / 4 + 255) / 256, 256, 0, stream>>>(in_proj_w, (unsigned short*)wA, nr, np); }
    { int n = D_MODEL * D_INNER;
      cvt_f32_bf16<<<(n / 4 + 255) / 256, 256, 0, stream>>>(out_proj_w, (unsigned short*)wO, n); }

    gemm_in_256<<<(NPROJPAD / 128) * (NTOK / 256), 512, 0, stream>>>(
        uB, wA, Zb, XBC, dtraw);

    conv_norm_v3<<<NTOK / 8, 256, 0, stream>>>(XBC, dtraw, conv_w, conv_b, norm_w, dt_bias,
                                               xy, Bb, Cb, dtb);

    score_kernel<<<NBC, 256, 0, stream>>>(Bb, Cb, Graw);
    chunk_state_mfma<<<NCHB, 256, 0, stream>>>(xy, Bb, dtb, A_log, states, cdecay);
    state_pass_kernel<<<BATCH * NHEADS, 256, 0, stream>>>(states, cdecay);
    chunk_output_mfma<<<NCHB, 256, 0, stream>>>(Zb, xy, Cb, Graw, dtb, A_log, Dp, states);

    gemm_out_mfma<D_MODEL / 128><<<(D_MODEL / 128) * (NTOK / 128), 256, 0, stream>>>(
        xy, wO, D_INNER, (float*)d_out);
}

// Round 15
// 261.605 us; speedup vs baseline: 1.0027x; 1.0027x over previous
//
#include <hip/hip_runtime.h>
#include <hip/hip_bf16.h>
#include <cstddef>

#define D_MODEL   384
#define D_IN_PROJ 1676
#define D_INNER   768
#define D_CONV_IN 896
#define ZXLD      1664
#define NPROJPAD  1792          // 14 * 128
#define NHEADS    12
#define HEADDIM   64
#define D_STATE   64
#define SEQLEN    4096
#define BATCH     8
#define NTOK      (BATCH * SEQLEN)
#define EPSV      1e-5f
#define Q         128
#define NCHUNK    (SEQLEN / Q)
#define NCHB      (BATCH * NHEADS * NCHUNK)
#define NBC       (BATCH * NCHUNK)

typedef __hip_bfloat16 bf16;
typedef __attribute__((ext_vector_type(8))) short bf16x8v;
typedef __attribute__((ext_vector_type(4))) float f32x4v;

__device__ __forceinline__ float b2f(bf16 v) { return __bfloat162float(v); }
__device__ __forceinline__ bf16  f2b(float v) { return __float2bfloat16(v); }
__device__ __forceinline__ float bl(unsigned u)  { return __uint_as_float(u << 16); }
__device__ __forceinline__ float bh(unsigned u)  { return __uint_as_float(u & 0xffff0000u); }
__device__ __forceinline__ float bu(unsigned short v) { return __uint_as_float(((unsigned)v) << 16); }
__device__ __forceinline__ unsigned pk2(float a, float b) {
    return ((unsigned)__bfloat16_as_ushort(f2b(b)) << 16) | (unsigned)__bfloat16_as_ushort(f2b(a));
}
__device__ __forceinline__ int swzf(int r) { return (r ^ (r >> 2)) & 3; }
__device__ __forceinline__ int tswz(int r, int col) {
    return r * 128 + ((((col >> 3) ^ (r & 7)) << 3) | (col & 7));
}

#define GL_LDS16(g, l) __builtin_amdgcn_global_load_lds( \
    (const __attribute__((address_space(1))) unsigned*)(g), \
    (__attribute__((address_space(3))) unsigned*)(l), 16, 0, 0)

// ---------------------------------------------------------------------------
__global__ __launch_bounds__(256)
void cvt_f32_bf16(const float* __restrict__ in, unsigned short* __restrict__ out, int n) {
    int i = (blockIdx.x * 256 + threadIdx.x) * 4;
    if (i + 3 < n) {
        float4 v = *(const float4*)(in + i);
        uint2 o; o.x = pk2(v.x, v.y); o.y = pk2(v.z, v.w);
        *(uint2*)(out + i) = o;
    }
}

__global__ __launch_bounds__(256)
void cvt_pad(const float* __restrict__ in, unsigned short* __restrict__ out,
             int n_real, int n_pad) {
    int i = (blockIdx.x * 256 + threadIdx.x) * 4;
    if (i + 3 < n_pad) {
        uint2 o;
        if (i < n_real) {
            float4 v = *(const float4*)(in + i);
            o.x = pk2(v.x, v.y); o.y = pk2(v.z, v.w);
        } else {
            o.x = 0u; o.y = 0u;
        }
        *(uint2*)(out + i) = o;
    }
}

// ---------------------------------------------------------------------------
// K1: MFMA GEMM-NT, 256x128 tile, 512 threads, BK=32 dbuf, XCD remap
// ---------------------------------------------------------------------------
__global__ __launch_bounds__(512)
void gemm_in_256(const bf16* __restrict__ A, const bf16* __restrict__ Bw,
                 bf16* __restrict__ Zo, bf16* __restrict__ XBCo,
                 float* __restrict__ Do) {
    const int K = D_MODEL;
    __shared__ short As[2][256 * 32];
    __shared__ short Bs[2][128 * 32];
    const int tid = threadIdx.x;
    const int lane = tid & 63;
    const int wv = tid >> 6;
    const int wr = wv >> 1;
    const int wc = wv & 1;

    const int id = blockIdx.x;
    const int xcd = id & 7;
    const int j = id >> 3;
    const int by = xcd + 8 * (j / 14);
    const int bx = j % 14;
    const int bm = by * 256;
    const int bn = bx * 128;

    f32x4v acc[4][4];
#pragma unroll
    for (int mi = 0; mi < 4; ++mi)
#pragma unroll
        for (int ni = 0; ni < 4; ++ni)
            acc[mi][ni] = (f32x4v){0.f, 0.f, 0.f, 0.f};

    int aoff[2], boff;
#pragma unroll
    for (int q = 0; q < 2; ++q) {
        int o = q * 8192 + tid * 16;
        int row = o >> 6;
        int ps = (o >> 4) & 3;
        int sl = ps ^ swzf(row);
        aoff[q] = (bm + row) * K + sl * 8;
    }
    {
        int o = tid * 16;
        int row = o >> 6;
        int ps = (o >> 4) & 3;
        int sl = ps ^ swzf(row);
        boff = (bn + row) * K + sl * 8;
    }

    const int l15 = lane & 15, qq = lane >> 4;
    int aidx[4], bidx[4];
#pragma unroll
    for (int i = 0; i < 4; ++i) {
        int ra = wr * 64 + i * 16 + l15;
        int rb = wc * 64 + i * 16 + l15;
        aidx[i] = ra * 32 + ((qq ^ swzf(ra)) * 8);
        bidx[i] = rb * 32 + ((qq ^ swzf(rb)) * 8);
    }

    GL_LDS16(A + (size_t)aoff[0], &As[0][tid * 8]);
    GL_LDS16(A + (size_t)aoff[1], &As[0][4096 + tid * 8]);
    GL_LDS16(Bw + (size_t)boff, &Bs[0][tid * 8]);
    __syncthreads();

    const int nt = K >> 5;
    for (int t = 0; t < nt; ++t) {
        const int cur = t & 1;
        if (t + 1 < nt) {
            const int k0 = (t + 1) << 5;
            GL_LDS16(A + (size_t)aoff[0] + k0, &As[cur ^ 1][tid * 8]);
            GL_LDS16(A + (size_t)aoff[1] + k0, &As[cur ^ 1][4096 + tid * 8]);
            GL_LDS16(Bw + (size_t)boff + k0, &Bs[cur ^ 1][tid * 8]);
        }
        bf16x8v af[4], bf[4];
#pragma unroll
        for (int i = 0; i < 4; ++i) {
            af[i] = *(const bf16x8v*)(&As[cur][aidx[i]]);
            bf[i] = *(const bf16x8v*)(&Bs[cur][bidx[i]]);
        }
#pragma unroll
        for (int mi = 0; mi < 4; ++mi)
#pragma unroll
            for (int ni = 0; ni < 4; ++ni)
                acc[mi][ni] = __builtin_amdgcn_mfma_f32_16x16x32_bf16(
                    af[mi], bf[ni], acc[mi][ni], 0, 0, 0);
        __syncthreads();
    }

    const int l4 = lane >> 4;
#pragma unroll
    for (int mi = 0; mi < 4; ++mi) {
        int rbase = bm + wr * 64 + mi * 16 + l4 * 4;
#pragma unroll
        for (int ni = 0; ni < 4; ++ni) {
            int col = bn + wc * 64 + ni * 16 + l15;
            f32x4v v = acc[mi][ni];
            if (col < D_INNER) {
#pragma unroll
                for (int jj = 0; jj < 4; ++jj)
                    Zo[(size_t)(rbase + jj) * D_INNER + col] = f2b(v[jj]);
            } else if (col < ZXLD) {
#pragma unroll
                for (int jj = 0; jj < 4; ++jj)
                    XBCo[(size_t)(rbase + jj) * D_CONV_IN + (col - D_INNER)] = f2b(v[jj]);
            } else if (col < D_IN_PROJ) {
#pragma unroll
                for (int jj = 0; jj < 4; ++jj)
                    Do[(size_t)(rbase + jj) * NHEADS + (col - ZXLD)] = v[jj];
            }
        }
    }
}

// ---------------------------------------------------------------------------
// K4: MFMA GEMM-NT 128x128, BK=32 dbuf, XCD remap (unchanged)
// ---------------------------------------------------------------------------
template<int NX>
__global__ __launch_bounds__(256)
void gemm_out_mfma(const bf16* __restrict__ A, const bf16* __restrict__ Bw, int K,
                   float* __restrict__ Co) {
    __shared__ short As[2][128 * 32];
    __shared__ short Bs[2][128 * 32];
    const int tid = threadIdx.x;
    const int lane = tid & 63;
    const int w = tid >> 6;
    const int wr = w >> 1, wc = w & 1;

    const int id = blockIdx.x;
    const int xcd = id & 7;
    const int j = id >> 3;
    const int by = xcd + 8 * (j / NX);
    const int bx = j % NX;
    const int bm = by * 128;
    const int bn = bx * 128;

    f32x4v acc[4][4];
#pragma unroll
    for (int mi = 0; mi < 4; ++mi)
#pragma unroll
        for (int ni = 0; ni < 4; ++ni)
            acc[mi][ni] = (f32x4v){0.f, 0.f, 0.f, 0.f};

    int aoff[2], boff[2];
#pragma unroll
    for (int q = 0; q < 2; ++q) {
        int o = q * 4096 + tid * 16;
        int row = o >> 6;
        int ps = (o >> 4) & 3;
        int sl = ps ^ swzf(row);
        aoff[q] = (bm + row) * K + sl * 8;
        boff[q] = (bn + row) * K + sl * 8;
    }

    const int l15 = lane & 15, qq = lane >> 4;
    int aidx[4], bidx[4];
#pragma unroll
    for (int i = 0; i < 4; ++i) {
        int ra = wr * 64 + i * 16 + l15;
        int rb = wc * 64 + i * 16 + l15;
        aidx[i] = ra * 32 + ((qq ^ swzf(ra)) * 8);
        bidx[i] = rb * 32 + ((qq ^ swzf(rb)) * 8);
    }

    GL_LDS16(A + (size_t)aoff[0], &As[0][tid * 8]);
    GL_LDS16(A + (size_t)aoff[1], &As[0][2048 + tid * 8]);
    GL_LDS16(Bw + (size_t)boff[0], &Bs[0][tid * 8]);
    GL_LDS16(Bw + (size_t)boff[1], &Bs[0][2048 + tid * 8]);
    __syncthreads();

    const int nt = K >> 5;
    for (int t = 0; t < nt; ++t) {
        const int cur = t & 1;
        if (t + 1 < nt) {
            const int k0 = (t + 1) << 5;
            GL_LDS16(A + (size_t)aoff[0] + k0, &As[cur ^ 1][tid * 8]);
            GL_LDS16(A + (size_t)aoff[1] + k0, &As[cur ^ 1][2048 + tid * 8]);
            GL_LDS16(Bw + (size_t)boff[0] + k0, &Bs[cur ^ 1][tid * 8]);
            GL_LDS16(Bw + (size_t)boff[1] + k0, &Bs[cur ^ 1][2048 + tid * 8]);
        }
        bf16x8v af[4], bf[4];
#pragma unroll
        for (int i = 0; i < 4; ++i) {
            af[i] = *(const bf16x8v*)(&As[cur][aidx[i]]);
            bf[i] = *(const bf16x8v*)(&Bs[cur][bidx[i]]);
        }
#pragma unroll
        for (int mi = 0; mi < 4; ++mi)
#pragma unroll
            for (int ni = 0; ni < 4; ++ni)
                acc[mi][ni] = __builtin_amdgcn_mfma_f32_16x16x32_bf16(
                    af[mi], bf[ni], acc[mi][ni], 0, 0, 0);
        __syncthreads();
    }

    const int l4 = lane >> 4;
#pragma unroll
    for (int mi = 0; mi < 4; ++mi) {
        int rbase = bm + wr * 64 + mi * 16 + l4 * 4;
#pragma unroll
        for (int ni = 0; ni < 4; ++ni) {
            int col = bn + wc * 64 + ni * 16 + l15;
            f32x4v v = acc[mi][ni];
#pragma unroll
            for (int jj = 0; jj < 4; ++jj)
                Co[(size_t)(rbase + jj) * D_MODEL + col] = v[jj];
        }
    }
}

// ---------------------------------------------------------------------------
// K2 v3 (unchanged)
// ---------------------------------------------------------------------------
__global__ __launch_bounds__(256)
void conv_norm_v3(const bf16* __restrict__ XBC, const float* __restrict__ dtraw,
                  const float* __restrict__ conv_w, const float* __restrict__ conv_b,
                  const float* __restrict__ norm_w, const float* __restrict__ dt_bias,
                  bf16* __restrict__ xn, bf16* __restrict__ Bb,
                  bf16* __restrict__ Cb, float* __restrict__ dtb) {
    const int tid = threadIdx.x;
    const int t0 = blockIdx.x * 8;
    const int l0 = t0 & (SEQLEN - 1);

    __shared__ float sp[8][200];
    __shared__ float sq[8][8];
    __shared__ float sscale[8];

    const int c = tid;
    const bool active = (c < 224);
    const int ch0 = c * 4;

    float acc[8][4];
    float w0[4], w1[4], w2[4], w3[4];

    if (active) {
        float4 wa = *(const float4*)(conv_w + (ch0 + 0) * 4);
        float4 wb = *(const float4*)(conv_w + (ch0 + 1) * 4);
        float4 wcc = *(const float4*)(conv_w + (ch0 + 2) * 4);
        float4 wd = *(const float4*)(conv_w + (ch0 + 3) * 4);
        w0[0] = wa.x; w1[0] = wa.y; w2[0] = wa.z; w3[0] = wa.w;
        w0[1] = wb.x; w1[1] = wb.y; w2[1] = wb.z; w3[1] = wb.w;
        w0[2] = wcc.x; w1[2] = wcc.y; w2[2] = wcc.z; w3[2] = wcc.w;
        w0[3] = wd.x; w1[3] = wd.y; w2[3] = wd.z; w3[3] = wd.w;
        float4 bv = *(const float4*)(conv_b + ch0);
#pragma unroll
        for (int t = 0; t < 8; ++t) {
            acc[t][0] = bv.x; acc[t][1] = bv.y; acc[t][2] = bv.z; acc[t][3] = bv.w;
        }
#pragma unroll
        for (int ri = 0; ri < 11; ++ri) {
            int lr = l0 - 3 + ri;
            if (lr >= 0) {
                uint2 rv = *(const uint2*)((const unsigned short*)XBC
                              + (size_t)(t0 - 3 + ri) * D_CONV_IN + ch0);
                float r0 = bl(rv.x), r1 = bh(rv.x), r2 = bl(rv.y), r3 = bh(rv.y);
#pragma unroll
                for (int t = 0; t < 8; ++t) {
                    if (t >= ri - 3 && t <= ri) {
                        const int jt = ri - t;
                        const float* wj = (jt == 0) ? w0 : (jt == 1) ? w1 : (jt == 2) ? w2 : w3;
                        acc[t][0] += r0 * wj[0];
                        acc[t][1] += r1 * wj[1];
                        acc[t][2] += r2 * wj[2];
                        acc[t][3] += r3 * wj[3];
                    }
                }
            }
        }
#pragma unroll
        for (int t = 0; t < 8; ++t) {
            float ss = 0.f;
#pragma unroll
            for (int i = 0; i < 4; ++i) {
                float v = acc[t][i];
                float s = v / (1.f + __expf(-v));
                acc[t][i] = s;
                ss += s * s;
            }
            if (c < 192) sp[t][c] = ss;
        }
    }
    __syncthreads();
    if (tid < 64) {
        int t = tid >> 3, i = tid & 7;
        float s = 0.f;
#pragma unroll
        for (int k = 0; k < 24; ++k) s += sp[t][i * 24 + k];
        sq[t][i] = s;
    }
    __syncthreads();
    if (tid < 8) {
        float tot = 0.f;
#pragma unroll
        for (int i = 0; i < 8; ++i) tot += sq[tid][i];
        sscale[tid] = rsqrtf(tot / (float)D_INNER + EPSV);
    }
    __syncthreads();

    if (c < 192) {
        float4 nv = *(const float4*)(norm_w + ch0);
#pragma unroll
        for (int t = 0; t < 8; ++t) {
            float sc = sscale[t];
            uint2 o;
            o.x = pk2(acc[t][0] * sc * nv.x, acc[t][1] * sc * nv.y);
            o.y = pk2(acc[t][2] * sc * nv.z, acc[t][3] * sc * nv.w);
            *(uint2*)(xn + (size_t)(t0 + t) * D_INNER + ch0) = o;
        }
    } else if (c < 224) {
        const int idx = ch0 - 768;
#pragma unroll
        for (int t = 0; t < 8; ++t) {
            uint2 o;
            o.x = pk2(acc[t][0], acc[t][1]);
            o.y = pk2(acc[t][2], acc[t][3]);
            bf16* base = (idx < 64) ? (Bb + (size_t)(t0 + t) * D_STATE + idx)
                                    : (Cb + (size_t)(t0 + t) * D_STATE + (idx - 64));
            *(uint2*)base = o;
        }
    }
    if (tid < 96) {
        int t = tid / 12, hh = tid % 12;
        float v = dtraw[(size_t)(t0 + t) * NHEADS + hh] + dt_bias[hh];
        float spv = (v > 20.f) ? v : log1pf(expf(v));
        dtb[(size_t)(t0 + t) * NHEADS + hh] = spv;
    }
}

// ---------------------------------------------------------------------------
// Score kernel (unchanged)
// ---------------------------------------------------------------------------
__global__ __launch_bounds__(256)
void score_kernel(const bf16* __restrict__ Bb, const bf16* __restrict__ Cb,
                  bf16* __restrict__ Graw) {
    const int bc = blockIdx.x;
    const size_t tok0 = (size_t)bc * Q;
    const int tid = threadIdx.x;
    const int lane = tid & 63, w = tid >> 6;
    const int wr = w >> 1, wc = w & 1;
    __shared__ short sC[Q * 64];
    __shared__ short sB[Q * 64];

#pragma unroll
    for (int it = 0; it < 4; ++it) {
        int j = it * 256 + tid;
        int r = j >> 3, sp = j & 7;
        int sl = sp ^ (r & 7);
        GL_LDS16(Cb + tok0 * D_STATE + r * 64 + sl * 8, sC + j * 8);
        GL_LDS16(Bb + tok0 * D_STATE + r * 64 + sl * 8, sB + j * 8);
    }
    __syncthreads();

    const int l15 = lane & 15, qq = lane >> 4;
    f32x4v acc[4][4];
#pragma unroll
    for (int mi = 0; mi < 4; ++mi)
#pragma unroll
        for (int ni = 0; ni < 4; ++ni)
            acc[mi][ni] = (f32x4v){0.f, 0.f, 0.f, 0.f};

#pragma unroll
    for (int kb = 0; kb < 2; ++kb) {
        bf16x8v af[4], bf[4];
#pragma unroll
        for (int i = 0; i < 4; ++i) {
            int ra = wr * 64 + i * 16 + l15;
            int rb = wc * 64 + i * 16 + l15;
            af[i] = *(const bf16x8v*)(sC + ra * 64 + ((kb * 4 + qq) ^ (ra & 7)) * 8);
            bf[i] = *(const bf16x8v*)(sB + rb * 64 + ((kb * 4 + qq) ^ (rb & 7)) * 8);
        }
#pragma unroll
        for (int mi = 0; mi < 4; ++mi)
#pragma unroll
            for (int ni = 0; ni < 4; ++ni)
                acc[mi][ni] = __builtin_amdgcn_mfma_f32_16x16x32_bf16(
                    af[mi], bf[ni], acc[mi][ni], 0, 0, 0);
    }

    bf16* gout = Graw + (size_t)bc * (Q * Q);
#pragma unroll
    for (int mi = 0; mi < 4; ++mi) {
        int t0 = wr * 64 + mi * 16 + qq * 4;
#pragma unroll
        for (int ni = 0; ni < 4; ++ni) {
            int s = wc * 64 + ni * 16 + l15;
            f32x4v v = acc[mi][ni];
#pragma unroll
            for (int j = 0; j < 4; ++j)
                gout[(size_t)(t0 + j) * Q + s] = f2b(v[j]);
        }
    }
}

// ---------------------------------------------------------------------------
// K3a (MFMA) (unchanged)
// ---------------------------------------------------------------------------
__global__ __launch_bounds__(256)
void chunk_state_mfma(const bf16* __restrict__ xy, const bf16* __restrict__ Bb,
                      const float* __restrict__ dtb, const float* __restrict__ A_log,
                      float* __restrict__ states, float* __restrict__ cdecay) {
    const int sid = blockIdx.x;
    const int c = sid % NCHUNK;
    const int h = (sid / NCHUNK) % NHEADS;
    const int b = sid / (NCHUNK * NHEADS);
    const int tid = threadIdx.x;
    const int lane = tid & 63, w = tid >> 6;
    const size_t tok0 = (size_t)b * SEQLEN + (size_t)c * Q;
    const float Acoef = -expf(A_log[h]);

    __shared__ __align__(16) unsigned short sBT[64 * 128];
    __shared__ __align__(16) unsigned short sXT[64 * 128];
    __shared__ float slcum[Q];
    __shared__ float sdt[Q];
    __shared__ float wtot[2];

    float lx = 0.f;
    if (tid < Q) {
        float dtv = dtb[(tok0 + tid) * NHEADS + h];
        sdt[tid] = dtv;
        lx = dtv * Acoef;
        int ln = tid & 63;
        for (int off = 1; off < 64; off <<= 1) {
            float v = __shfl_up(lx, off, 64);
            if (ln >= off) lx += v;
        }
        if (ln == 63) wtot[tid >> 6] = lx;
    }
    __syncthreads();
    if (tid < Q) {
        if (tid >= 64) lx += wtot[0];
        slcum[tid] = lx;
    }
    __syncthreads();
    const float ltot = slcum[Q - 1];

    {
        int t = tid >> 1, half = tid & 1;
        float s_t = sdt[t] * __expf(ltot - slcum[t]);
        const unsigned short* br = (const unsigned short*)(Bb + (tok0 + t) * D_STATE) + half * 32;
        const unsigned short* xr = (const unsigned short*)(xy + (tok0 + t) * D_INNER + h * HEADDIM) + half * 32;
#pragma unroll
        for (int i = 0; i < 32; ++i) {
            int r = half * 32 + i;
            sBT[tswz(r, t)] = __bfloat16_as_ushort(f2b(bu(br[i]) * s_t));
            sXT[tswz(r, t)] = xr[i];
        }
    }
    __syncthreads();

    const int l15 = lane & 15, qq = lane >> 4;
    f32x4v acc[4];
#pragma unroll
    for (int ni = 0; ni < 4; ++ni) acc[ni] = (f32x4v){0.f, 0.f, 0.f, 0.f};

#pragma unroll
    for (int kb = 0; kb < 4; ++kb) {
        const int col = kb * 32 + qq * 8;
        bf16x8v af = *(const bf16x8v*)(&sBT[tswz(w * 16 + l15, col)]);
#pragma unroll
        for (int ni = 0; ni < 4; ++ni) {
            bf16x8v bx = *(const bf16x8v*)(&sXT[tswz(ni * 16 + l15, col)]);
            acc[ni] = __builtin_amdgcn_mfma_f32_16x16x32_bf16(af, bx, acc[ni], 0, 0, 0);
        }
    }

    float* out = states + (size_t)sid * 4096;
#pragma unroll
    for (int ni = 0; ni < 4; ++ni) {
#pragma unroll
        for (int j = 0; j < 4; ++j) {
            int n = w * 16 + qq * 4 + j;
            int p = ni * 16 + l15;
            out[n * 64 + p] = acc[ni][j];
        }
    }
    if (tid == 0) cdecay[sid] = expf(ltot);
}

// ---------------------------------------------------------------------------
// K3b (unchanged)
// ---------------------------------------------------------------------------
__global__ __launch_bounds__(256)
void state_pass_kernel(float* __restrict__ states, const float* __restrict__ cdecay) {
    const int bh = blockIdx.x;
    const int tid = threadIdx.x;
    float run[16];
#pragma unroll
    for (int i = 0; i < 16; ++i) run[i] = 0.f;
    float* base = states + (size_t)bh * NCHUNK * 4096 + tid * 16;
    const float* cd = cdecay + bh * NCHUNK;
    for (int c = 0; c < NCHUNK; ++c) {
        float dec = cd[c];
        float* ptr = base + (size_t)c * 4096;
        float4 s0 = *(float4*)(ptr + 0);
        float4 s1 = *(float4*)(ptr + 4);
        float4 s2 = *(float4*)(ptr + 8);
        float4 s3 = *(float4*)(ptr + 12);
        float nr[16];
        nr[0] = dec * run[0] + s0.x;  nr[1] = dec * run[1] + s0.y;
        nr[2] = dec * run[2] + s0.z;  nr[3] = dec * run[3] + s0.w;
        nr[4] = dec * run[4] + s1.x;  nr[5] = dec * run[5] + s1.y;
        nr[6] = dec * run[6] + s1.z;  nr[7] = dec * run[7] + s1.w;
        nr[8] = dec * run[8] + s2.x;  nr[9] = dec * run[9] + s2.y;
        nr[10] = dec * run[10] + s2.z; nr[11] = dec * run[11] + s2.w;
        nr[12] = dec * run[12] + s3.x; nr[13] = dec * run[13] + s3.y;
        nr[14] = dec * run[14] + s3.z; nr[15] = dec * run[15] + s3.w;
        *(float4*)(ptr + 0)  = make_float4(run[0], run[1], run[2], run[3]);
        *(float4*)(ptr + 4)  = make_float4(run[4], run[5], run[6], run[7]);
        *(float4*)(ptr + 8)  = make_float4(run[8], run[9], run[10], run[11]);
        *(float4*)(ptr + 12) = make_float4(run[12], run[13], run[14], run[15]);
#pragma unroll
        for (int i = 0; i < 16; ++i) run[i] = nr[i];
    }
}

// ---------------------------------------------------------------------------
// K3c v4 (MFMA): per-sub-block exp factorization.
// factor(t,s) = exp(lct - b_kb) * sE[s],  sE[s] = exp(b_kb(s) - lcs) * dt_s.
// One exp per (row,kb) instead of one per element.
// ---------------------------------------------------------------------------
__global__ __launch_bounds__(256)
void chunk_output_mfma(const bf16* __restrict__ Zb, bf16* __restrict__ xy,
                       const bf16* __restrict__ Cb, const bf16* __restrict__ Graw,
                       const float* __restrict__ dtb, const float* __restrict__ A_log,
                       const float* __restrict__ Dpa, const float* __restrict__ states) {
    // head-clustered bijective remap
    const int id = blockIdx.x;
    const int xcd = id & 7;
    const int jg = id >> 3;
    const int bcg = xcd * 32 + (jg / NHEADS);
    const int h = jg % NHEADS;
    const int b = bcg / NCHUNK;
    const int c = bcg % NCHUNK;
    const int sid = (b * NHEADS + h) * NCHUNK + c;
    const int bc = bcg;
    const int tid = threadIdx.x;
    const int lane = tid & 63, w = tid >> 6;
    const size_t tok0 = (size_t)b * SEQLEN + (size_t)c * Q;
    const float Acoef = -expf(A_log[h]);

    __shared__ __align__(16) char smem[35840];
    unsigned short (*sXt)[136] = (unsigned short(*)[136])smem;
    unsigned short (*sNh)[72]  = (unsigned short(*)[72])(smem + 17408);
    unsigned short (*sNl)[72]  = (unsigned short(*)[72])(smem + 17408 + 9216);
    float (*sY)[68] = (float(*)[68])smem;
    __shared__ float slc[Q];
    __shared__ float sE[Q];
    __shared__ float wtot[2];

    // --- phase 1: cumulative log-decay scan -> slc ---
    float lx = 0.f, dtv = 0.f;
    if (tid < Q) {
        dtv = dtb[(tok0 + tid) * NHEADS + h];
        lx = dtv * Acoef;
        int ln = tid & 63;
        for (int off = 1; off < 64; off <<= 1) {
            float v = __shfl_up(lx, off, 64);
            if (ln >= off) lx += v;
        }
        if (ln == 63) wtot[tid >> 6] = lx;
    }
    __syncthreads();
    if (tid < Q) {
        if (tid >= 64) lx += wtot[0];
        slc[tid] = lx;
    }
    __syncthreads();   // slc complete before sE reads block bases

    // --- phase 2: sE + stage X^T + stage init ---
    if (tid < Q) {
        float basev = slc[tid & ~31];
        sE[tid] = __expf(basev - lx) * dtv;
    }
    {
        int tp = tid & 63;
        int rh = tid >> 6;
        union { uint4 u[2]; unsigned short s[16]; } va, vb;
        const unsigned short* x0 = (const unsigned short*)(xy + (tok0 + 2 * tp) * D_INNER + h * HEADDIM + rh * 16);
        const unsigned short* x1 = (const unsigned short*)(xy + (tok0 + 2 * tp + 1) * D_INNER + h * HEADDIM + rh * 16);
        va.u[0] = *(const uint4*)(x0);  va.u[1] = *(const uint4*)(x0 + 8);
        vb.u[0] = *(const uint4*)(x1);  vb.u[1] = *(const uint4*)(x1 + 8);
#pragma unroll
        for (int i = 0; i < 16; ++i) {
            unsigned pack = (unsigned)va.s[i] | ((unsigned)vb.s[i] << 16);
            *(unsigned*)(&sXt[rh * 16 + i][2 * tp]) = pack;
        }
    }
    {
        const float* init = states + (size_t)sid * 4096;
        for (int i = tid; i < 1024; i += 256) {
            float4 v = ((const float4*)init)[i];
            int n = i >> 4;
            int p = (i & 15) * 4;
#pragma unroll
            for (int j2 = 0; j2 < 4; ++j2) {
                float f = (&v.x)[j2];
                bf16 hi = f2b(f);
                float lo = f - b2f(hi);
                sNh[p + j2][n] = __bfloat16_as_ushort(hi);
                sNl[p + j2][n] = __bfloat16_as_ushort(f2b(lo));
            }
        }
    }
    __syncthreads();

    const int l15 = lane & 15, qq = lane >> 4;

    int tcur[2]; float lct_mi[2], elct[2];
#pragma unroll
    for (int mi = 0; mi < 2; ++mi) {
        tcur[mi] = w * 32 + mi * 16 + l15;
        lct_mi[mi] = slc[tcur[mi]];
        elct[mi] = __expf(lct_mi[mi]);
    }

    f32x4v acc[2][4];
#pragma unroll
    for (int mi = 0; mi < 2; ++mi)
#pragma unroll
        for (int ni = 0; ni < 4; ++ni)
            acc[mi][ni] = (f32x4v){0.f, 0.f, 0.f, 0.f};

    const bf16* grow = Graw + (size_t)bc * (Q * Q);

#pragma unroll
    for (int kb = 0; kb < 4; ++kb) {
        const int s0 = kb * 32 + qq * 8;
        const float bbase = slc[kb * 32];
        float4 eA = *(const float4*)(sE + s0);
        float4 eB = *(const float4*)(sE + s0 + 4);
        bf16x8v af[2];
#pragma unroll
        for (int mi = 0; mi < 2; ++mi) {
            int t = tcur[mi];
            float g = __expf(fminf(lct_mi[mi] - bbase, 0.f));
            uint4 gv = *(const uint4*)(grow + (size_t)t * Q + s0);
            float f0 = (s0 + 0 <= t) ? bl(gv.x) * g * eA.x : 0.f;
            float f1 = (s0 + 1 <= t) ? bh(gv.x) * g * eA.y : 0.f;
            float f2 = (s0 + 2 <= t) ? bl(gv.y) * g * eA.z : 0.f;
            float f3 = (s0 + 3 <= t) ? bh(gv.y) * g * eA.w : 0.f;
            float f4 = (s0 + 4 <= t) ? bl(gv.z) * g * eB.x : 0.f;
            float f5 = (s0 + 5 <= t) ? bh(gv.z) * g * eB.y : 0.f;
            float f6 = (s0 + 6 <= t) ? bl(gv.w) * g * eB.z : 0.f;
            float f7 = (s0 + 7 <= t) ? bh(gv.w) * g * eB.w : 0.f;
            union { bf16x8v v; unsigned u[4]; } r;
            r.u[0] = pk2(f0, f1); r.u[1] = pk2(f2, f3);
            r.u[2] = pk2(f4, f5); r.u[3] = pk2(f6, f7);
            af[mi] = r.v;
        }
        bf16x8v bfr[4];
#pragma unroll
        for (int ni = 0; ni < 4; ++ni)
            bfr[ni] = *(const bf16x8v*)(&sXt[ni * 16 + l15][s0]);
#pragma unroll
        for (int mi = 0; mi < 2; ++mi)
#pragma unroll
            for (int ni = 0; ni < 4; ++ni)
                acc[mi][ni] = __builtin_amdgcn_mfma_f32_16x16x32_bf16(
                    af[mi], bfr[ni], acc[mi][ni], 0, 0, 0);
    }

#pragma unroll
    for (int half = 0; half < 2; ++half) {
        const int n0 = half * 32 + qq * 8;
        bf16x8v af[2];
#pragma unroll
        for (int mi = 0; mi < 2; ++mi) {
            uint4 cv = *(const uint4*)(Cb + (tok0 + tcur[mi]) * D_STATE + n0);
            float el = elct[mi];
            union { bf16x8v v; unsigned u[4]; } r;
            r.u[0] = pk2(bl(cv.x) * el, bh(cv.x) * el);
            r.u[1] = pk2(bl(cv.y) * el, bh(cv.y) * el);
            r.u[2] = pk2(bl(cv.z) * el, bh(cv.z) * el);
            r.u[3] = pk2(bl(cv.w) * el, bh(cv.w) * el);
            af[mi] = r.v;
        }
        bf16x8v bh_[4], bl_[4];
#pragma unroll
        for (int ni = 0; ni < 4; ++ni) {
            int p = ni * 16 + l15;
            bh_[ni] = *(const bf16x8v*)(&sNh[p][n0]);
            bl_[ni] = *(const bf16x8v*)(&sNl[p][n0]);
        }
#pragma unroll
        for (int mi = 0; mi < 2; ++mi)
#pragma unroll
            for (int ni = 0; ni < 4; ++ni) {
                acc[mi][ni] = __builtin_amdgcn_mfma_f32_16x16x32_bf16(
                    af[mi], bh_[ni], acc[mi][ni], 0, 0, 0);
                acc[mi][ni] = __builtin_amdgcn_mfma_f32_16x16x32_bf16(
                    af[mi], bl_[ni], acc[mi][ni], 0, 0, 0);
            }
    }

    __syncthreads();
#pragma unroll
    for (int mi = 0; mi < 2; ++mi) {
        int r0 = w * 32 + mi * 16 + qq * 4;
#pragma unroll
        for (int ni = 0; ni < 4; ++ni) {
            int p = ni * 16 + l15;
            f32x4v v = acc[mi][ni];
#pragma unroll
            for (int jj = 0; jj < 4; ++jj) sY[r0 + jj][p] = v[jj];
        }
    }
    __syncthreads();

    {
        const float Dh = Dpa[h];
        int t = tid >> 1;
        int p0 = (tid & 1) * 32;
        size_t off = (tok0 + t) * D_INNER + h * HEADDIM + p0;
        const uint4* xrow = (const uint4*)(xy + off);
        const uint4* zrow = (const uint4*)(Zb + off);
        uint4 outv[4];
#pragma unroll
        for (int k4 = 0; k4 < 4; ++k4) {
            uint4 xv = xrow[k4];
            uint4 zv = zrow[k4];
            const float* yr = &sY[t][p0 + k4 * 8];
            float xs[8] = {bl(xv.x), bh(xv.x), bl(xv.y), bh(xv.y),
                           bl(xv.z), bh(xv.z), bl(xv.w), bh(xv.w)};
            float zs[8] = {bl(zv.x), bh(zv.x), bl(zv.y), bh(zv.y),
                           bl(zv.z), bh(zv.z), bl(zv.w), bh(zv.w)};
            unsigned o[4];
#pragma unroll
            for (int j = 0; j < 4; ++j) {
                float y0 = yr[2 * j]     + Dh * xs[2 * j];
                float y1 = yr[2 * j + 1] + Dh * xs[2 * j + 1];
                float z0 = zs[2 * j], z1 = zs[2 * j + 1];
                y0 *= z0 / (1.f + __expf(-z0));
                y1 *= z1 / (1.f + __expf(-z1));
                o[j] = pk2(y0, y1);
            }
            outv[k4].x = o[0]; outv[k4].y = o[1]; outv[k4].z = o[2]; outv[k4].w = o[3];
        }
        uint4* orow = (uint4*)(xy + off);
#pragma unroll
        for (int k4 = 0; k4 < 4; ++k4) orow[k4] = outv[k4];
    }
}

// ---------------------------------------------------------------------------
extern "C" void kernel_launch(void* const* d_in, const int* in_sizes, int n_in,
                              void* d_out, int out_size, void* d_ws, size_t ws_size,
                              hipStream_t stream) {
    (void)in_sizes; (void)n_in; (void)out_size; (void)ws_size;
    const float* u          = (const float*)d_in[0];
    const float* in_proj_w  = (const float*)d_in[1];
    const float* conv_w     = (const float*)d_in[2];
    const float* conv_b     = (const float*)d_in[3];
    const float* norm_w     = (const float*)d_in[4];
    const float* out_proj_w = (const float*)d_in[5];
    const float* A_log      = (const float*)d_in[6];
    const float* Dp         = (const float*)d_in[7];
    const float* dt_bias    = (const float*)d_in[8];

    char* w = (char*)d_ws;
    bf16*  Zb     = (bf16*)w;     w += (size_t)NTOK * D_INNER * 2;
    bf16*  XBC    = (bf16*)w;     w += (size_t)NTOK * D_CONV_IN * 2;
    bf16*  xy     = (bf16*)w;     w += (size_t)NTOK * D_INNER * 2;
    bf16*  Bb     = (bf16*)w;     w += (size_t)NTOK * D_STATE * 2;
    bf16*  Cb     = (bf16*)w;     w += (size_t)NTOK * D_STATE * 2;
    float* dtraw  = (float*)w;    w += (size_t)NTOK * NHEADS * 4;
    float* dtb    = (float*)w;    w += (size_t)NTOK * NHEADS * 4;
    float* cdecay = (float*)w;    w += (size_t)NCHB * 4;
    bf16*  wA     = (bf16*)w;     w += (size_t)NPROJPAD * D_MODEL * 2;
    bf16*  wO     = (bf16*)w;
    float* states = (float*)XBC;
    bf16*  Graw   = (bf16*)((char*)XBC + (size_t)NCHB * 4096 * 4);
    bf16*  uB     = xy;

    { int n = NTOK * D_MODEL;
      cvt_f32_bf16<<<(n / 4 + 255) / 256, 256, 0, stream>>>(u, (unsigned short*)uB, n); }
    { int nr = D_IN_PROJ * D_MODEL, np = NPROJPAD * D_MODEL;
      cvt_pad<<<(np / 4 + 255) / 256, 256, 0, stream>>>(in_proj_w, (unsigned short*)wA, nr, np); }
    { int n = D_MODEL * D_INNER;
      cvt_f32_bf16<<<(n / 4 + 255) / 256, 256, 0, stream>>>(out_proj_w, (unsigned short*)wO, n); }

    gemm_in_256<<<(NPROJPAD / 128) * (NTOK / 256), 512, 0, stream>>>(
        uB, wA, Zb, XBC, dtraw);

    conv_norm_v3<<<NTOK / 8, 256, 0, stream>>>(XBC, dtraw, conv_w, conv_b, norm_w, dt_bias,
                                               xy, Bb, Cb, dtb);

    score_kernel<<<NBC, 256, 0, stream>>>(Bb, Cb, Graw);
    chunk_state_mfma<<<NCHB, 256, 0, stream>>>(xy, Bb, dtb, A_log, states, cdecay);
    state_pass_kernel<<<BATCH * NHEADS, 256, 0, stream>>>(states, cdecay);
    chunk_output_mfma<<<NCHB, 256, 0, stream>>>(Zb, xy, Cb, Graw, dtb, A_log, Dp, states);

    gemm_out_mfma<D_MODEL / 128><<<(D_MODEL / 128) * (NTOK / 128), 256, 0, stream>>>(
        xy, wO, D_INNER, (float*)d_out);
}

// Round 16
// 256.519 us; speedup vs baseline: 1.0226x; 1.0198x over previous
//
#include <hip/hip_runtime.h>
#include <hip/hip_bf16.h>
#include <cstddef>

#define D_MODEL   384
#define D_IN_PROJ 1676
#define D_INNER   768
#define D_CONV_IN 896
#define ZXLD      1664
#define NPROJPAD  1792          // 14 * 128
#define NHEADS    12
#define HEADDIM   64
#define D_STATE   64
#define SEQLEN    4096
#define BATCH     8
#define NTOK      (BATCH * SEQLEN)
#define EPSV      1e-5f
#define Q         128
#define NCHUNK    (SEQLEN / Q)
#define NCHB      (BATCH * NHEADS * NCHUNK)
#define NBC       (BATCH * NCHUNK)

typedef __hip_bfloat16 bf16;
typedef __attribute__((ext_vector_type(8))) short bf16x8v;
typedef __attribute__((ext_vector_type(4))) float f32x4v;

__device__ __forceinline__ float b2f(bf16 v) { return __bfloat162float(v); }
__device__ __forceinline__ bf16  f2b(float v) { return __float2bfloat16(v); }
__device__ __forceinline__ float bl(unsigned u)  { return __uint_as_float(u << 16); }
__device__ __forceinline__ float bh(unsigned u)  { return __uint_as_float(u & 0xffff0000u); }
__device__ __forceinline__ float bu(unsigned short v) { return __uint_as_float(((unsigned)v) << 16); }
__device__ __forceinline__ unsigned pk2(float a, float b) {
    return ((unsigned)__bfloat16_as_ushort(f2b(b)) << 16) | (unsigned)__bfloat16_as_ushort(f2b(a));
}
__device__ __forceinline__ int swzf(int r) { return (r ^ (r >> 2)) & 3; }
__device__ __forceinline__ int tswz(int r, int col) {
    return r * 128 + ((((col >> 3) ^ (r & 7)) << 3) | (col & 7));
}

#define GL_LDS16(g, l) __builtin_amdgcn_global_load_lds( \
    (const __attribute__((address_space(1))) unsigned*)(g), \
    (__attribute__((address_space(3))) unsigned*)(l), 16, 0, 0)

// ---------------------------------------------------------------------------
__global__ __launch_bounds__(256)
void cvt_f32_bf16(const float* __restrict__ in, unsigned short* __restrict__ out, int n) {
    int i = (blockIdx.x * 256 + threadIdx.x) * 4;
    if (i + 3 < n) {
        float4 v = *(const float4*)(in + i);
        uint2 o; o.x = pk2(v.x, v.y); o.y = pk2(v.z, v.w);
        *(uint2*)(out + i) = o;
    }
}

__global__ __launch_bounds__(256)
void cvt_pad(const float* __restrict__ in, unsigned short* __restrict__ out,
             int n_real, int n_pad) {
    int i = (blockIdx.x * 256 + threadIdx.x) * 4;
    if (i + 3 < n_pad) {
        uint2 o;
        if (i < n_real) {
            float4 v = *(const float4*)(in + i);
            o.x = pk2(v.x, v.y); o.y = pk2(v.z, v.w);
        } else {
            o.x = 0u; o.y = 0u;
        }
        *(uint2*)(out + i) = o;
    }
}

// ---------------------------------------------------------------------------
// K1: MFMA GEMM-NT, 256x128 tile, 512 threads, BK=32 dbuf, XCD remap
// ---------------------------------------------------------------------------
__global__ __launch_bounds__(512)
void gemm_in_256(const bf16* __restrict__ A, const bf16* __restrict__ Bw,
                 bf16* __restrict__ Zo, bf16* __restrict__ XBCo,
                 float* __restrict__ Do) {
    const int K = D_MODEL;
    __shared__ short As[2][256 * 32];
    __shared__ short Bs[2][128 * 32];
    const int tid = threadIdx.x;
    const int lane = tid & 63;
    const int wv = tid >> 6;
    const int wr = wv >> 1;
    const int wc = wv & 1;

    const int id = blockIdx.x;
    const int xcd = id & 7;
    const int j = id >> 3;
    const int by = xcd + 8 * (j / 14);
    const int bx = j % 14;
    const int bm = by * 256;
    const int bn = bx * 128;

    f32x4v acc[4][4];
#pragma unroll
    for (int mi = 0; mi < 4; ++mi)
#pragma unroll
        for (int ni = 0; ni < 4; ++ni)
            acc[mi][ni] = (f32x4v){0.f, 0.f, 0.f, 0.f};

    int aoff[2], boff;
#pragma unroll
    for (int q = 0; q < 2; ++q) {
        int o = q * 8192 + tid * 16;
        int row = o >> 6;
        int ps = (o >> 4) & 3;
        int sl = ps ^ swzf(row);
        aoff[q] = (bm + row) * K + sl * 8;
    }
    {
        int o = tid * 16;
        int row = o >> 6;
        int ps = (o >> 4) & 3;
        int sl = ps ^ swzf(row);
        boff = (bn + row) * K + sl * 8;
    }

    const int l15 = lane & 15, qq = lane >> 4;
    int aidx[4], bidx[4];
#pragma unroll
    for (int i = 0; i < 4; ++i) {
        int ra = wr * 64 + i * 16 + l15;
        int rb = wc * 64 + i * 16 + l15;
        aidx[i] = ra * 32 + ((qq ^ swzf(ra)) * 8);
        bidx[i] = rb * 32 + ((qq ^ swzf(rb)) * 8);
    }

    GL_LDS16(A + (size_t)aoff[0], &As[0][tid * 8]);
    GL_LDS16(A + (size_t)aoff[1], &As[0][4096 + tid * 8]);
    GL_LDS16(Bw + (size_t)boff, &Bs[0][tid * 8]);
    __syncthreads();

    const int nt = K >> 5;
    for (int t = 0; t < nt; ++t) {
        const int cur = t & 1;
        if (t + 1 < nt) {
            const int k0 = (t + 1) << 5;
            GL_LDS16(A + (size_t)aoff[0] + k0, &As[cur ^ 1][tid * 8]);
            GL_LDS16(A + (size_t)aoff[1] + k0, &As[cur ^ 1][4096 + tid * 8]);
            GL_LDS16(Bw + (size_t)boff + k0, &Bs[cur ^ 1][tid * 8]);
        }
        bf16x8v af[4], bf[4];
#pragma unroll
        for (int i = 0; i < 4; ++i) {
            af[i] = *(const bf16x8v*)(&As[cur][aidx[i]]);
            bf[i] = *(const bf16x8v*)(&Bs[cur][bidx[i]]);
        }
#pragma unroll
        for (int mi = 0; mi < 4; ++mi)
#pragma unroll
            for (int ni = 0; ni < 4; ++ni)
                acc[mi][ni] = __builtin_amdgcn_mfma_f32_16x16x32_bf16(
                    af[mi], bf[ni], acc[mi][ni], 0, 0, 0);
        __syncthreads();
    }

    const int l4 = lane >> 4;
#pragma unroll
    for (int mi = 0; mi < 4; ++mi) {
        int rbase = bm + wr * 64 + mi * 16 + l4 * 4;
#pragma unroll
        for (int ni = 0; ni < 4; ++ni) {
            int col = bn + wc * 64 + ni * 16 + l15;
            f32x4v v = acc[mi][ni];
            if (col < D_INNER) {
#pragma unroll
                for (int jj = 0; jj < 4; ++jj)
                    Zo[(size_t)(rbase + jj) * D_INNER + col] = f2b(v[jj]);
            } else if (col < ZXLD) {
#pragma unroll
                for (int jj = 0; jj < 4; ++jj)
                    XBCo[(size_t)(rbase + jj) * D_CONV_IN + (col - D_INNER)] = f2b(v[jj]);
            } else if (col < D_IN_PROJ) {
#pragma unroll
                for (int jj = 0; jj < 4; ++jj)
                    Do[(size_t)(rbase + jj) * NHEADS + (col - ZXLD)] = v[jj];
            }
        }
    }
}

// ---------------------------------------------------------------------------
// K4: MFMA GEMM-NT 128x128, BK=32 dbuf, XCD remap (unchanged)
// ---------------------------------------------------------------------------
template<int NX>
__global__ __launch_bounds__(256)
void gemm_out_mfma(const bf16* __restrict__ A, const bf16* __restrict__ Bw, int K,
                   float* __restrict__ Co) {
    __shared__ short As[2][128 * 32];
    __shared__ short Bs[2][128 * 32];
    const int tid = threadIdx.x;
    const int lane = tid & 63;
    const int w = tid >> 6;
    const int wr = w >> 1, wc = w & 1;

    const int id = blockIdx.x;
    const int xcd = id & 7;
    const int j = id >> 3;
    const int by = xcd + 8 * (j / NX);
    const int bx = j % NX;
    const int bm = by * 128;
    const int bn = bx * 128;

    f32x4v acc[4][4];
#pragma unroll
    for (int mi = 0; mi < 4; ++mi)
#pragma unroll
        for (int ni = 0; ni < 4; ++ni)
            acc[mi][ni] = (f32x4v){0.f, 0.f, 0.f, 0.f};

    int aoff[2], boff[2];
#pragma unroll
    for (int q = 0; q < 2; ++q) {
        int o = q * 4096 + tid * 16;
        int row = o >> 6;
        int ps = (o >> 4) & 3;
        int sl = ps ^ swzf(row);
        aoff[q] = (bm + row) * K + sl * 8;
        boff[q] = (bn + row) * K + sl * 8;
    }

    const int l15 = lane & 15, qq = lane >> 4;
    int aidx[4], bidx[4];
#pragma unroll
    for (int i = 0; i < 4; ++i) {
        int ra = wr * 64 + i * 16 + l15;
        int rb = wc * 64 + i * 16 + l15;
        aidx[i] = ra * 32 + ((qq ^ swzf(ra)) * 8);
        bidx[i] = rb * 32 + ((qq ^ swzf(rb)) * 8);
    }

    GL_LDS16(A + (size_t)aoff[0], &As[0][tid * 8]);
    GL_LDS16(A + (size_t)aoff[1], &As[0][2048 + tid * 8]);
    GL_LDS16(Bw + (size_t)boff[0], &Bs[0][tid * 8]);
    GL_LDS16(Bw + (size_t)boff[1], &Bs[0][2048 + tid * 8]);
    __syncthreads();

    const int nt = K >> 5;
    for (int t = 0; t < nt; ++t) {
        const int cur = t & 1;
        if (t + 1 < nt) {
            const int k0 = (t + 1) << 5;
            GL_LDS16(A + (size_t)aoff[0] + k0, &As[cur ^ 1][tid * 8]);
            GL_LDS16(A + (size_t)aoff[1] + k0, &As[cur ^ 1][2048 + tid * 8]);
            GL_LDS16(Bw + (size_t)boff[0] + k0, &Bs[cur ^ 1][tid * 8]);
            GL_LDS16(Bw + (size_t)boff[1] + k0, &Bs[cur ^ 1][2048 + tid * 8]);
        }
        bf16x8v af[4], bf[4];
#pragma unroll
        for (int i = 0; i < 4; ++i) {
            af[i] = *(const bf16x8v*)(&As[cur][aidx[i]]);
            bf[i] = *(const bf16x8v*)(&Bs[cur][bidx[i]]);
        }
#pragma unroll
        for (int mi = 0; mi < 4; ++mi)
#pragma unroll
            for (int ni = 0; ni < 4; ++ni)
                acc[mi][ni] = __builtin_amdgcn_mfma_f32_16x16x32_bf16(
                    af[mi], bf[ni], acc[mi][ni], 0, 0, 0);
        __syncthreads();
    }

    const int l4 = lane >> 4;
#pragma unroll
    for (int mi = 0; mi < 4; ++mi) {
        int rbase = bm + wr * 64 + mi * 16 + l4 * 4;
#pragma unroll
        for (int ni = 0; ni < 4; ++ni) {
            int col = bn + wc * 64 + ni * 16 + l15;
            f32x4v v = acc[mi][ni];
#pragma unroll
            for (int jj = 0; jj < 4; ++jj)
                Co[(size_t)(rbase + jj) * D_MODEL + col] = v[jj];
        }
    }
}

// ---------------------------------------------------------------------------
// K2 v3 (unchanged)
// ---------------------------------------------------------------------------
__global__ __launch_bounds__(256)
void conv_norm_v3(const bf16* __restrict__ XBC, const float* __restrict__ dtraw,
                  const float* __restrict__ conv_w, const float* __restrict__ conv_b,
                  const float* __restrict__ norm_w, const float* __restrict__ dt_bias,
                  bf16* __restrict__ xn, bf16* __restrict__ Bb,
                  bf16* __restrict__ Cb, float* __restrict__ dtb) {
    const int tid = threadIdx.x;
    const int t0 = blockIdx.x * 8;
    const int l0 = t0 & (SEQLEN - 1);

    __shared__ float sp[8][200];
    __shared__ float sq[8][8];
    __shared__ float sscale[8];

    const int c = tid;
    const bool active = (c < 224);
    const int ch0 = c * 4;

    float acc[8][4];
    float w0[4], w1[4], w2[4], w3[4];

    if (active) {
        float4 wa = *(const float4*)(conv_w + (ch0 + 0) * 4);
        float4 wb = *(const float4*)(conv_w + (ch0 + 1) * 4);
        float4 wcc = *(const float4*)(conv_w + (ch0 + 2) * 4);
        float4 wd = *(const float4*)(conv_w + (ch0 + 3) * 4);
        w0[0] = wa.x; w1[0] = wa.y; w2[0] = wa.z; w3[0] = wa.w;
        w0[1] = wb.x; w1[1] = wb.y; w2[1] = wb.z; w3[1] = wb.w;
        w0[2] = wcc.x; w1[2] = wcc.y; w2[2] = wcc.z; w3[2] = wcc.w;
        w0[3] = wd.x; w1[3] = wd.y; w2[3] = wd.z; w3[3] = wd.w;
        float4 bv = *(const float4*)(conv_b + ch0);
#pragma unroll
        for (int t = 0; t < 8; ++t) {
            acc[t][0] = bv.x; acc[t][1] = bv.y; acc[t][2] = bv.z; acc[t][3] = bv.w;
        }
#pragma unroll
        for (int ri = 0; ri < 11; ++ri) {
            int lr = l0 - 3 + ri;
            if (lr >= 0) {
                uint2 rv = *(const uint2*)((const unsigned short*)XBC
                              + (size_t)(t0 - 3 + ri) * D_CONV_IN + ch0);
                float r0 = bl(rv.x), r1 = bh(rv.x), r2 = bl(rv.y), r3 = bh(rv.y);
#pragma unroll
                for (int t = 0; t < 8; ++t) {
                    if (t >= ri - 3 && t <= ri) {
                        const int jt = ri - t;
                        const float* wj = (jt == 0) ? w0 : (jt == 1) ? w1 : (jt == 2) ? w2 : w3;
                        acc[t][0] += r0 * wj[0];
                        acc[t][1] += r1 * wj[1];
                        acc[t][2] += r2 * wj[2];
                        acc[t][3] += r3 * wj[3];
                    }
                }
            }
        }
#pragma unroll
        for (int t = 0; t < 8; ++t) {
            float ss = 0.f;
#pragma unroll
            for (int i = 0; i < 4; ++i) {
                float v = acc[t][i];
                float s = v / (1.f + __expf(-v));
                acc[t][i] = s;
                ss += s * s;
            }
            if (c < 192) sp[t][c] = ss;
        }
    }
    __syncthreads();
    if (tid < 64) {
        int t = tid >> 3, i = tid & 7;
        float s = 0.f;
#pragma unroll
        for (int k = 0; k < 24; ++k) s += sp[t][i * 24 + k];
        sq[t][i] = s;
    }
    __syncthreads();
    if (tid < 8) {
        float tot = 0.f;
#pragma unroll
        for (int i = 0; i < 8; ++i) tot += sq[tid][i];
        sscale[tid] = rsqrtf(tot / (float)D_INNER + EPSV);
    }
    __syncthreads();

    if (c < 192) {
        float4 nv = *(const float4*)(norm_w + ch0);
#pragma unroll
        for (int t = 0; t < 8; ++t) {
            float sc = sscale[t];
            uint2 o;
            o.x = pk2(acc[t][0] * sc * nv.x, acc[t][1] * sc * nv.y);
            o.y = pk2(acc[t][2] * sc * nv.z, acc[t][3] * sc * nv.w);
            *(uint2*)(xn + (size_t)(t0 + t) * D_INNER + ch0) = o;
        }
    } else if (c < 224) {
        const int idx = ch0 - 768;
#pragma unroll
        for (int t = 0; t < 8; ++t) {
            uint2 o;
            o.x = pk2(acc[t][0], acc[t][1]);
            o.y = pk2(acc[t][2], acc[t][3]);
            bf16* base = (idx < 64) ? (Bb + (size_t)(t0 + t) * D_STATE + idx)
                                    : (Cb + (size_t)(t0 + t) * D_STATE + (idx - 64));
            *(uint2*)base = o;
        }
    }
    if (tid < 96) {
        int t = tid / 12, hh = tid % 12;
        float v = dtraw[(size_t)(t0 + t) * NHEADS + hh] + dt_bias[hh];
        float spv = (v > 20.f) ? v : log1pf(expf(v));
        dtb[(size_t)(t0 + t) * NHEADS + hh] = spv;
    }
}

// ---------------------------------------------------------------------------
// Score kernel (unchanged)
// ---------------------------------------------------------------------------
__global__ __launch_bounds__(256)
void score_kernel(const bf16* __restrict__ Bb, const bf16* __restrict__ Cb,
                  bf16* __restrict__ Graw) {
    const int bc = blockIdx.x;
    const size_t tok0 = (size_t)bc * Q;
    const int tid = threadIdx.x;
    const int lane = tid & 63, w = tid >> 6;
    const int wr = w >> 1, wc = w & 1;
    __shared__ short sC[Q * 64];
    __shared__ short sB[Q * 64];

#pragma unroll
    for (int it = 0; it < 4; ++it) {
        int j = it * 256 + tid;
        int r = j >> 3, sp = j & 7;
        int sl = sp ^ (r & 7);
        GL_LDS16(Cb + tok0 * D_STATE + r * 64 + sl * 8, sC + j * 8);
        GL_LDS16(Bb + tok0 * D_STATE + r * 64 + sl * 8, sB + j * 8);
    }
    __syncthreads();

    const int l15 = lane & 15, qq = lane >> 4;
    f32x4v acc[4][4];
#pragma unroll
    for (int mi = 0; mi < 4; ++mi)
#pragma unroll
        for (int ni = 0; ni < 4; ++ni)
            acc[mi][ni] = (f32x4v){0.f, 0.f, 0.f, 0.f};

#pragma unroll
    for (int kb = 0; kb < 2; ++kb) {
        bf16x8v af[4], bf[4];
#pragma unroll
        for (int i = 0; i < 4; ++i) {
            int ra = wr * 64 + i * 16 + l15;
            int rb = wc * 64 + i * 16 + l15;
            af[i] = *(const bf16x8v*)(sC + ra * 64 + ((kb * 4 + qq) ^ (ra & 7)) * 8);
            bf[i] = *(const bf16x8v*)(sB + rb * 64 + ((kb * 4 + qq) ^ (rb & 7)) * 8);
        }
#pragma unroll
        for (int mi = 0; mi < 4; ++mi)
#pragma unroll
            for (int ni = 0; ni < 4; ++ni)
                acc[mi][ni] = __builtin_amdgcn_mfma_f32_16x16x32_bf16(
                    af[mi], bf[ni], acc[mi][ni], 0, 0, 0);
    }

    bf16* gout = Graw + (size_t)bc * (Q * Q);
#pragma unroll
    for (int mi = 0; mi < 4; ++mi) {
        int t0 = wr * 64 + mi * 16 + qq * 4;
#pragma unroll
        for (int ni = 0; ni < 4; ++ni) {
            int s = wc * 64 + ni * 16 + l15;
            f32x4v v = acc[mi][ni];
#pragma unroll
            for (int j = 0; j < 4; ++j)
                gout[(size_t)(t0 + j) * Q + s] = f2b(v[j]);
        }
    }
}

// ---------------------------------------------------------------------------
// K3a (MFMA) (unchanged)
// ---------------------------------------------------------------------------
__global__ __launch_bounds__(256)
void chunk_state_mfma(const bf16* __restrict__ xy, const bf16* __restrict__ Bb,
                      const float* __restrict__ dtb, const float* __restrict__ A_log,
                      float* __restrict__ states, float* __restrict__ cdecay) {
    const int sid = blockIdx.x;
    const int c = sid % NCHUNK;
    const int h = (sid / NCHUNK) % NHEADS;
    const int b = sid / (NCHUNK * NHEADS);
    const int tid = threadIdx.x;
    const int lane = tid & 63, w = tid >> 6;
    const size_t tok0 = (size_t)b * SEQLEN + (size_t)c * Q;
    const float Acoef = -expf(A_log[h]);

    __shared__ __align__(16) unsigned short sBT[64 * 128];
    __shared__ __align__(16) unsigned short sXT[64 * 128];
    __shared__ float slcum[Q];
    __shared__ float sdt[Q];
    __shared__ float wtot[2];

    float lx = 0.f;
    if (tid < Q) {
        float dtv = dtb[(tok0 + tid) * NHEADS + h];
        sdt[tid] = dtv;
        lx = dtv * Acoef;
        int ln = tid & 63;
        for (int off = 1; off < 64; off <<= 1) {
            float v = __shfl_up(lx, off, 64);
            if (ln >= off) lx += v;
        }
        if (ln == 63) wtot[tid >> 6] = lx;
    }
    __syncthreads();
    if (tid < Q) {
        if (tid >= 64) lx += wtot[0];
        slcum[tid] = lx;
    }
    __syncthreads();
    const float ltot = slcum[Q - 1];

    {
        int t = tid >> 1, half = tid & 1;
        float s_t = sdt[t] * __expf(ltot - slcum[t]);
        const unsigned short* br = (const unsigned short*)(Bb + (tok0 + t) * D_STATE) + half * 32;
        const unsigned short* xr = (const unsigned short*)(xy + (tok0 + t) * D_INNER + h * HEADDIM) + half * 32;
#pragma unroll
        for (int i = 0; i < 32; ++i) {
            int r = half * 32 + i;
            sBT[tswz(r, t)] = __bfloat16_as_ushort(f2b(bu(br[i]) * s_t));
            sXT[tswz(r, t)] = xr[i];
        }
    }
    __syncthreads();

    const int l15 = lane & 15, qq = lane >> 4;
    f32x4v acc[4];
#pragma unroll
    for (int ni = 0; ni < 4; ++ni) acc[ni] = (f32x4v){0.f, 0.f, 0.f, 0.f};

#pragma unroll
    for (int kb = 0; kb < 4; ++kb) {
        const int col = kb * 32 + qq * 8;
        bf16x8v af = *(const bf16x8v*)(&sBT[tswz(w * 16 + l15, col)]);
#pragma unroll
        for (int ni = 0; ni < 4; ++ni) {
            bf16x8v bx = *(const bf16x8v*)(&sXT[tswz(ni * 16 + l15, col)]);
            acc[ni] = __builtin_amdgcn_mfma_f32_16x16x32_bf16(af, bx, acc[ni], 0, 0, 0);
        }
    }

    float* out = states + (size_t)sid * 4096;
#pragma unroll
    for (int ni = 0; ni < 4; ++ni) {
#pragma unroll
        for (int j = 0; j < 4; ++j) {
            int n = w * 16 + qq * 4 + j;
            int p = ni * 16 + l15;
            out[n * 64 + p] = acc[ni][j];
        }
    }
    if (tid == 0) cdecay[sid] = expf(ltot);
}

// ---------------------------------------------------------------------------
// K3b (unchanged)
// ---------------------------------------------------------------------------
__global__ __launch_bounds__(256)
void state_pass_kernel(float* __restrict__ states, const float* __restrict__ cdecay) {
    const int bh = blockIdx.x;
    const int tid = threadIdx.x;
    float run[16];
#pragma unroll
    for (int i = 0; i < 16; ++i) run[i] = 0.f;
    float* base = states + (size_t)bh * NCHUNK * 4096 + tid * 16;
    const float* cd = cdecay + bh * NCHUNK;
    for (int c = 0; c < NCHUNK; ++c) {
        float dec = cd[c];
        float* ptr = base + (size_t)c * 4096;
        float4 s0 = *(float4*)(ptr + 0);
        float4 s1 = *(float4*)(ptr + 4);
        float4 s2 = *(float4*)(ptr + 8);
        float4 s3 = *(float4*)(ptr + 12);
        float nr[16];
        nr[0] = dec * run[0] + s0.x;  nr[1] = dec * run[1] + s0.y;
        nr[2] = dec * run[2] + s0.z;  nr[3] = dec * run[3] + s0.w;
        nr[4] = dec * run[4] + s1.x;  nr[5] = dec * run[5] + s1.y;
        nr[6] = dec * run[6] + s1.z;  nr[7] = dec * run[7] + s1.w;
        nr[8] = dec * run[8] + s2.x;  nr[9] = dec * run[9] + s2.y;
        nr[10] = dec * run[10] + s2.z; nr[11] = dec * run[11] + s2.w;
        nr[12] = dec * run[12] + s3.x; nr[13] = dec * run[13] + s3.y;
        nr[14] = dec * run[14] + s3.z; nr[15] = dec * run[15] + s3.w;
        *(float4*)(ptr + 0)  = make_float4(run[0], run[1], run[2], run[3]);
        *(float4*)(ptr + 4)  = make_float4(run[4], run[5], run[6], run[7]);
        *(float4*)(ptr + 8)  = make_float4(run[8], run[9], run[10], run[11]);
        *(float4*)(ptr + 12) = make_float4(run[12], run[13], run[14], run[15]);
#pragma unroll
        for (int i = 0; i < 16; ++i) run[i] = nr[i];
    }
}

// ---------------------------------------------------------------------------
// K3c v5 (MFMA): Dp folded into the mask diagonal (removes epilogue x re-read);
// sY stride 67 (conflict-free epilogue reads).
// ---------------------------------------------------------------------------
__global__ __launch_bounds__(256)
void chunk_output_mfma(const bf16* __restrict__ Zb, bf16* __restrict__ xy,
                       const bf16* __restrict__ Cb, const bf16* __restrict__ Graw,
                       const float* __restrict__ dtb, const float* __restrict__ A_log,
                       const float* __restrict__ Dpa, const float* __restrict__ states) {
    // head-clustered bijective remap
    const int id = blockIdx.x;
    const int xcd = id & 7;
    const int jg = id >> 3;
    const int bcg = xcd * 32 + (jg / NHEADS);
    const int h = jg % NHEADS;
    const int b = bcg / NCHUNK;
    const int c = bcg % NCHUNK;
    const int sid = (b * NHEADS + h) * NCHUNK + c;
    const int bc = bcg;
    const int tid = threadIdx.x;
    const int lane = tid & 63, w = tid >> 6;
    const size_t tok0 = (size_t)b * SEQLEN + (size_t)c * Q;
    const float Acoef = -expf(A_log[h]);
    const float Dh = Dpa[h];

    __shared__ __align__(16) char smem[35840];
    unsigned short (*sXt)[136] = (unsigned short(*)[136])smem;
    unsigned short (*sNh)[72]  = (unsigned short(*)[72])(smem + 17408);
    unsigned short (*sNl)[72]  = (unsigned short(*)[72])(smem + 17408 + 9216);
    float (*sY)[67] = (float(*)[67])smem;           // 128*67*4 = 34304 B
    __shared__ float slc[Q];
    __shared__ float sE[Q];
    __shared__ float wtot[2];

    // --- phase 1: cumulative log-decay scan -> slc ---
    float lx = 0.f, dtv = 0.f;
    if (tid < Q) {
        dtv = dtb[(tok0 + tid) * NHEADS + h];
        lx = dtv * Acoef;
        int ln = tid & 63;
        for (int off = 1; off < 64; off <<= 1) {
            float v = __shfl_up(lx, off, 64);
            if (ln >= off) lx += v;
        }
        if (ln == 63) wtot[tid >> 6] = lx;
    }
    __syncthreads();
    if (tid < Q) {
        if (tid >= 64) lx += wtot[0];
        slc[tid] = lx;
    }
    __syncthreads();

    // --- phase 2: sE + stage X^T + stage init ---
    if (tid < Q) {
        float basev = slc[tid & ~31];
        sE[tid] = __expf(basev - lx) * dtv;
    }
    {
        int tp = tid & 63;
        int rh = tid >> 6;
        union { uint4 u[2]; unsigned short s[16]; } va, vb;
        const unsigned short* x0 = (const unsigned short*)(xy + (tok0 + 2 * tp) * D_INNER + h * HEADDIM + rh * 16);
        const unsigned short* x1 = (const unsigned short*)(xy + (tok0 + 2 * tp + 1) * D_INNER + h * HEADDIM + rh * 16);
        va.u[0] = *(const uint4*)(x0);  va.u[1] = *(const uint4*)(x0 + 8);
        vb.u[0] = *(const uint4*)(x1);  vb.u[1] = *(const uint4*)(x1 + 8);
#pragma unroll
        for (int i = 0; i < 16; ++i) {
            unsigned pack = (unsigned)va.s[i] | ((unsigned)vb.s[i] << 16);
            *(unsigned*)(&sXt[rh * 16 + i][2 * tp]) = pack;
        }
    }
    {
        const float* init = states + (size_t)sid * 4096;
        for (int i = tid; i < 1024; i += 256) {
            float4 v = ((const float4*)init)[i];
            int n = i >> 4;
            int p = (i & 15) * 4;
#pragma unroll
            for (int j2 = 0; j2 < 4; ++j2) {
                float f = (&v.x)[j2];
                bf16 hi = f2b(f);
                float lo = f - b2f(hi);
                sNh[p + j2][n] = __bfloat16_as_ushort(hi);
                sNl[p + j2][n] = __bfloat16_as_ushort(f2b(lo));
            }
        }
    }
    __syncthreads();

    const int l15 = lane & 15, qq = lane >> 4;

    int tcur[2]; float lct_mi[2], elct[2];
#pragma unroll
    for (int mi = 0; mi < 2; ++mi) {
        tcur[mi] = w * 32 + mi * 16 + l15;
        lct_mi[mi] = slc[tcur[mi]];
        elct[mi] = __expf(lct_mi[mi]);
    }

    f32x4v acc[2][4];
#pragma unroll
    for (int mi = 0; mi < 2; ++mi)
#pragma unroll
        for (int ni = 0; ni < 4; ++ni)
            acc[mi][ni] = (f32x4v){0.f, 0.f, 0.f, 0.f};

    const bf16* grow = Graw + (size_t)bc * (Q * Q);

#pragma unroll
    for (int kb = 0; kb < 4; ++kb) {
        const int s0 = kb * 32 + qq * 8;
        const float bbase = slc[kb * 32];
        float4 eA = *(const float4*)(sE + s0);
        float4 eB = *(const float4*)(sE + s0 + 4);
        bf16x8v af[2];
#pragma unroll
        for (int mi = 0; mi < 2; ++mi) {
            int t = tcur[mi];
            float g = __expf(fminf(lct_mi[mi] - bbase, 0.f));
            uint4 gv = *(const uint4*)(grow + (size_t)t * Q + s0);
            float f0 = (s0 + 0 <= t) ? bl(gv.x) * g * eA.x : 0.f;
            float f1 = (s0 + 1 <= t) ? bh(gv.x) * g * eA.y : 0.f;
            float f2 = (s0 + 2 <= t) ? bl(gv.y) * g * eA.z : 0.f;
            float f3 = (s0 + 3 <= t) ? bh(gv.y) * g * eA.w : 0.f;
            float f4 = (s0 + 4 <= t) ? bl(gv.z) * g * eB.x : 0.f;
            float f5 = (s0 + 5 <= t) ? bh(gv.z) * g * eB.y : 0.f;
            float f6 = (s0 + 6 <= t) ? bl(gv.w) * g * eB.z : 0.f;
            float f7 = (s0 + 7 <= t) ? bh(gv.w) * g * eB.w : 0.f;
            // Dp folded into the diagonal: y += Dp * x_t
            if (s0 + 0 == t) f0 += Dh;
            if (s0 + 1 == t) f1 += Dh;
            if (s0 + 2 == t) f2 += Dh;
            if (s0 + 3 == t) f3 += Dh;
            if (s0 + 4 == t) f4 += Dh;
            if (s0 + 5 == t) f5 += Dh;
            if (s0 + 6 == t) f6 += Dh;
            if (s0 + 7 == t) f7 += Dh;
            union { bf16x8v v; unsigned u[4]; } r;
            r.u[0] = pk2(f0, f1); r.u[1] = pk2(f2, f3);
            r.u[2] = pk2(f4, f5); r.u[3] = pk2(f6, f7);
            af[mi] = r.v;
        }
        bf16x8v bfr[4];
#pragma unroll
        for (int ni = 0; ni < 4; ++ni)
            bfr[ni] = *(const bf16x8v*)(&sXt[ni * 16 + l15][s0]);
#pragma unroll
        for (int mi = 0; mi < 2; ++mi)
#pragma unroll
            for (int ni = 0; ni < 4; ++ni)
                acc[mi][ni] = __builtin_amdgcn_mfma_f32_16x16x32_bf16(
                    af[mi], bfr[ni], acc[mi][ni], 0, 0, 0);
    }

#pragma unroll
    for (int half = 0; half < 2; ++half) {
        const int n0 = half * 32 + qq * 8;
        bf16x8v af[2];
#pragma unroll
        for (int mi = 0; mi < 2; ++mi) {
            uint4 cv = *(const uint4*)(Cb + (tok0 + tcur[mi]) * D_STATE + n0);
            float el = elct[mi];
            union { bf16x8v v; unsigned u[4]; } r;
            r.u[0] = pk2(bl(cv.x) * el, bh(cv.x) * el);
            r.u[1] = pk2(bl(cv.y) * el, bh(cv.y) * el);
            r.u[2] = pk2(bl(cv.z) * el, bh(cv.z) * el);
            r.u[3] = pk2(bl(cv.w) * el, bh(cv.w) * el);
            af[mi] = r.v;
        }
        bf16x8v bh_[4], bl_[4];
#pragma unroll
        for (int ni = 0; ni < 4; ++ni) {
            int p = ni * 16 + l15;
            bh_[ni] = *(const bf16x8v*)(&sNh[p][n0]);
            bl_[ni] = *(const bf16x8v*)(&sNl[p][n0]);
        }
#pragma unroll
        for (int mi = 0; mi < 2; ++mi)
#pragma unroll
            for (int ni = 0; ni < 4; ++ni) {
                acc[mi][ni] = __builtin_amdgcn_mfma_f32_16x16x32_bf16(
                    af[mi], bh_[ni], acc[mi][ni], 0, 0, 0);
                acc[mi][ni] = __builtin_amdgcn_mfma_f32_16x16x32_bf16(
                    af[mi], bl_[ni], acc[mi][ni], 0, 0, 0);
            }
    }

    __syncthreads();
#pragma unroll
    for (int mi = 0; mi < 2; ++mi) {
        int r0 = w * 32 + mi * 16 + qq * 4;
#pragma unroll
        for (int ni = 0; ni < 4; ++ni) {
            int p = ni * 16 + l15;
            f32x4v v = acc[mi][ni];
#pragma unroll
            for (int jj = 0; jj < 4; ++jj) sY[r0 + jj][p] = v[jj];
        }
    }
    __syncthreads();

    {
        int t = tid >> 1;
        int p0 = (tid & 1) * 32;
        size_t off = (tok0 + t) * D_INNER + h * HEADDIM + p0;
        const uint4* zrow = (const uint4*)(Zb + off);
        uint4 outv[4];
#pragma unroll
        for (int k4 = 0; k4 < 4; ++k4) {
            uint4 zv = zrow[k4];
            const float* yr = &sY[t][p0 + k4 * 8];
            float zs[8] = {bl(zv.x), bh(zv.x), bl(zv.y), bh(zv.y),
                           bl(zv.z), bh(zv.z), bl(zv.w), bh(zv.w)};
            unsigned o[4];
#pragma unroll
            for (int j = 0; j < 4; ++j) {
                float y0 = yr[2 * j];
                float y1 = yr[2 * j + 1];
                float z0 = zs[2 * j], z1 = zs[2 * j + 1];
                y0 *= z0 / (1.f + __expf(-z0));
                y1 *= z1 / (1.f + __expf(-z1));
                o[j] = pk2(y0, y1);
            }
            outv[k4].x = o[0]; outv[k4].y = o[1]; outv[k4].z = o[2]; outv[k4].w = o[3];
        }
        uint4* orow = (uint4*)(xy + off);
#pragma unroll
        for (int k4 = 0; k4 < 4; ++k4) orow[k4] = outv[k4];
    }
}

// ---------------------------------------------------------------------------
extern "C" void kernel_launch(void* const* d_in, const int* in_sizes, int n_in,
                              void* d_out, int out_size, void* d_ws, size_t ws_size,
                              hipStream_t stream) {
    (void)in_sizes; (void)n_in; (void)out_size; (void)ws_size;
    const float* u          = (const float*)d_in[0];
    const float* in_proj_w  = (const float*)d_in[1];
    const float* conv_w     = (const float*)d_in[2];
    const float* conv_b     = (const float*)d_in[3];
    const float* norm_w     = (const float*)d_in[4];
    const float* out_proj_w = (const float*)d_in[5];
    const float* A_log      = (const float*)d_in[6];
    const float* Dp         = (const float*)d_in[7];
    const float* dt_bias    = (const float*)d_in[8];

    char* w = (char*)d_ws;
    bf16*  Zb     = (bf16*)w;     w += (size_t)NTOK * D_INNER * 2;
    bf16*  XBC    = (bf16*)w;     w += (size_t)NTOK * D_CONV_IN * 2;
    bf16*  xy     = (bf16*)w;     w += (size_t)NTOK * D_INNER * 2;
    bf16*  Bb     = (bf16*)w;     w += (size_t)NTOK * D_STATE * 2;
    bf16*  Cb     = (bf16*)w;     w += (size_t)NTOK * D_STATE * 2;
    float* dtraw  = (float*)w;    w += (size_t)NTOK * NHEADS * 4;
    float* dtb    = (float*)w;    w += (size_t)NTOK * NHEADS * 4;
    float* cdecay = (float*)w;    w += (size_t)NCHB * 4;
    bf16*  wA     = (bf16*)w;     w += (size_t)NPROJPAD * D_MODEL * 2;
    bf16*  wO     = (bf16*)w;
    float* states = (float*)XBC;
    bf16*  Graw   = (bf16*)((char*)XBC + (size_t)NCHB * 4096 * 4);
    bf16*  uB     = xy;

    { int n = NTOK * D_MODEL;
      cvt_f32_bf16<<<(n / 4 + 255) / 256, 256, 0, stream>>>(u, (unsigned short*)uB, n); }
    { int nr = D_IN_PROJ * D_MODEL, np = NPROJPAD * D_MODEL;
      cvt_pad<<<(np / 4 + 255) / 256, 256, 0, stream>>>(in_proj_w, (unsigned short*)wA, nr, np); }
    { int n = D_MODEL * D_INNER;
      cvt_f32_bf16<<<(n / 4 + 255) / 256, 256, 0, stream>>>(out_proj_w, (unsigned short*)wO, n); }

    gemm_in_256<<<(NPROJPAD / 128) * (NTOK / 256), 512, 0, stream>>>(
        uB, wA, Zb, XBC, dtraw);

    conv_norm_v3<<<NTOK / 8, 256, 0, stream>>>(XBC, dtraw, conv_w, conv_b, norm_w, dt_bias,
                                               xy, Bb, Cb, dtb);

    score_kernel<<<NBC, 256, 0, stream>>>(Bb, Cb, Graw);
    chunk_state_mfma<<<NCHB, 256, 0, stream>>>(xy, Bb, dtb, A_log, states, cdecay);
    state_pass_kernel<<<BATCH * NHEADS, 256, 0, stream>>>(states, cdecay);
    chunk_output_mfma<<<NCHB, 256, 0, stream>>>(Zb, xy, Cb, Graw, dtb, A_log, Dp, states);

    gemm_out_mfma<D_MODEL / 128><<<(D_MODEL / 128) * (NTOK / 128), 256, 0, stream>>>(
        xy, wO, D_INNER, (float*)d_out);
}